// Round 1
// baseline (967.627 us; speedup 1.0000x reference)
//
#include <hip/hip_runtime.h>
#include <cstdint>

typedef _Float16 h4 __attribute__((ext_vector_type(4)));
typedef _Float16 h8 __attribute__((ext_vector_type(8)));
typedef float f32x4 __attribute__((ext_vector_type(4)));
typedef float f32x16 __attribute__((ext_vector_type(16)));

// ---------- async global->LDS, 16B per lane, wave-uniform LDS base ----------
__device__ __forceinline__ void g2l16(const void* g, void* l) {
  __builtin_amdgcn_global_load_lds(
      (__attribute__((address_space(1))) void*)(uintptr_t)(g),
      (__attribute__((address_space(3))) void*)(l), 16, 0, 0);
}

// A/B fragment for mfma_*_x32 (BK=32 chunk): k(g,j) = 4g+j (j0..3), 16+4g+(j-4) (j4..7)
__device__ __forceinline__ h8 frag16(const _Float16* row, int g) {
  h4 lo = *(const h4*)(row + 4 * g);
  h4 hi = *(const h4*)(row + 16 + 4 * g);
  return __builtin_shufflevector(lo, hi, 0, 1, 2, 3, 4, 5, 6, 7);
}

// ---------------- fp32 -> fp16 elementwise ----------------
__global__ __launch_bounds__(256) void convk(const float* __restrict__ in,
                                             _Float16* __restrict__ out, int n) {
  int i = (blockIdx.x * 256 + threadIdx.x) * 4;
  if (i + 3 < n) {
    const float4 v = *(const float4*)(in + i);
    h4 o;
    o[0] = (_Float16)v.x; o[1] = (_Float16)v.y; o[2] = (_Float16)v.z; o[3] = (_Float16)v.w;
    *(h4*)(out + i) = o;
  }
}

// ---------------- fp32 [R][C] -> fp16 [C][R] transpose-convert ----------------
__global__ __launch_bounds__(256) void transconv_k(const float* __restrict__ in,
                                                   _Float16* __restrict__ out,
                                                   int R, int C) {
  __shared__ float tile[64][65];
  const int tC = C >> 6;
  const int bc = blockIdx.x % tC, br = blockIdx.x / tC;
  const int r0 = br << 6, c0 = bc << 6;
  const int t = threadIdx.x;
  const int lr = t >> 4, lc = (t & 15) << 2;
#pragma unroll
  for (int p = 0; p < 4; ++p) {
    const float4 v = *(const float4*)(in + (size_t)(r0 + p * 16 + lr) * C + c0 + lc);
    tile[p * 16 + lr][lc + 0] = v.x;
    tile[p * 16 + lr][lc + 1] = v.y;
    tile[p * 16 + lr][lc + 2] = v.z;
    tile[p * 16 + lr][lc + 3] = v.w;
  }
  __syncthreads();
#pragma unroll
  for (int p = 0; p < 4; ++p) {
    const int oc = p * 16 + lr;  // out-row = in-col
    h4 v;
#pragma unroll
    for (int e = 0; e < 4; ++e) v[e] = (_Float16)tile[lc + e][oc];
    *(h4*)(out + (size_t)(c0 + oc) * R + r0 + lc) = v;
  }
}

// ---------------- GEMM: C[M][N] = A[M][K] * BT[N][K]^T  (fp16 in, fp32 acc) ----------------
// MODE 0: plain fp32 store to fo (N = NTILES*128)
// MODE 1: QKV epilogue: l2norm + rope -> outq/outk [bh][n][64]; v -> outv [bh][64][n]
template <int MODE>
__global__ __launch_bounds__(256) void gemm_k(
    const _Float16* __restrict__ A, const _Float16* __restrict__ BT,
    const int K, const int NTILES,
    _Float16* __restrict__ outq, _Float16* __restrict__ outk,
    _Float16* __restrict__ outv, const float* __restrict__ freqs,
    float* __restrict__ fo) {
  __shared__ __align__(16) _Float16 As[128 * 32];
  __shared__ __align__(16) _Float16 Bs[128 * 32];
  const int tid = threadIdx.x;
  const int bt = blockIdx.x % NTILES;
  const int mb = blockIdx.x / NTILES;
  const int m0 = mb * 128, n0 = bt * 128;
  const int wid = tid >> 6, lane = tid & 63;
  const int wr = wid >> 1, wc = wid & 1;
  const int g = lane >> 4, c = lane & 15;

  f32x4 acc[4][4];
#pragma unroll
  for (int i = 0; i < 4; ++i)
#pragma unroll
    for (int j = 0; j < 4; ++j)
#pragma unroll
      for (int e = 0; e < 4; ++e) acc[i][j][e] = 0.f;

  const int ldr = tid >> 2;
  const int lko = (tid & 3) * 8;
  const _Float16* ag = A + (size_t)(m0 + ldr) * K + lko;
  const _Float16* bg = BT + (size_t)(n0 + ldr) * K + lko;
  _Float16* asw = As + wid * 512;
  _Float16* bsw = Bs + wid * 512;
  const size_t rowhop = (size_t)64 * K;

  const int nk = K >> 5;
  for (int kt = 0; kt < nk; ++kt) {
    __syncthreads();  // previous tile fully consumed
    const int kof = kt << 5;
    g2l16(ag + kof, asw);
    g2l16(ag + rowhop + kof, asw + 2048);
    g2l16(bg + kof, bsw);
    g2l16(bg + rowhop + kof, bsw + 2048);
    __syncthreads();  // staging drained (vmcnt(0) before barrier)
    h8 af[4], bf[4];
#pragma unroll
    for (int t = 0; t < 4; ++t) af[t] = frag16(As + (wr * 64 + t * 16 + c) * 32, g);
#pragma unroll
    for (int t = 0; t < 4; ++t) bf[t] = frag16(Bs + (wc * 64 + t * 16 + c) * 32, g);
#pragma unroll
    for (int i = 0; i < 4; ++i)
#pragma unroll
      for (int j = 0; j < 4; ++j)
        acc[i][j] = __builtin_amdgcn_mfma_f32_16x16x32_f16(af[i], bf[j], acc[i][j], 0, 0, 0);
  }

  if (MODE == 0) {
    const int Ncols = NTILES * 128;
#pragma unroll
    for (int mt = 0; mt < 4; ++mt)
#pragma unroll
      for (int i = 0; i < 4; ++i) {
        const int m = m0 + wr * 64 + mt * 16 + 4 * g + i;
        float* orow = fo + (size_t)m * Ncols + n0 + wc * 64 + c;
#pragma unroll
        for (int nt = 0; nt < 4; ++nt) orow[nt * 16] = acc[mt][nt][i];
      }
  } else {
    const int hh = ((bt & 15) << 1) | wc;  // head 0..31 within its third
    const int third = bt >> 4;             // 0=q 1=k 2=v
    if (third < 2) {
      _Float16* dst0 = (third == 0) ? outq : outk;
#pragma unroll
      for (int mt = 0; mt < 4; ++mt) {
        float ss[4];
#pragma unroll
        for (int i = 0; i < 4; ++i) {
          float s = 0.f;
#pragma unroll
          for (int nt = 0; nt < 4; ++nt) { const float v = acc[mt][nt][i]; s += v * v; }
          ss[i] = s;
        }
#pragma unroll
        for (int msk = 1; msk < 16; msk <<= 1)
#pragma unroll
          for (int i = 0; i < 4; ++i) ss[i] += __shfl_xor(ss[i], msk);
#pragma unroll
        for (int i = 0; i < 4; ++i) {
          const int m = m0 + wr * 64 + mt * 16 + 4 * g + i;
          const int b = m >> 11, pos = m & 2047;
          const float inv = 1.0f / fmaxf(sqrtf(ss[i]), 1e-12f);
          const float v0 = acc[mt][0][i] * inv, v1 = acc[mt][1][i] * inv;
          const float v2 = acc[mt][2][i] * inv, v3 = acc[mt][3][i] * inv;
          float sn, cs;
          __sincosf(freqs[pos * 32 + c], &sn, &cs);
          _Float16* d = dst0 + (((size_t)((b << 5) | hh) * 2048 + pos) << 6);
          d[c]      = (_Float16)(v0 * cs - v1 * sn);
          d[16 + c] = (_Float16)(v1 * cs + v0 * sn);
          d[32 + c] = (_Float16)v2;
          d[48 + c] = (_Float16)v3;
        }
      }
    } else {
#pragma unroll
      for (int mt = 0; mt < 4; ++mt)
#pragma unroll
        for (int i = 0; i < 4; ++i) {
          const int m = m0 + wr * 64 + mt * 16 + 4 * g + i;
          const int b = m >> 11, pos = m & 2047;
          const size_t hb = (size_t)((b << 5) | hh) * 64;
#pragma unroll
          for (int nt = 0; nt < 4; ++nt)
            outv[(hb + nt * 16 + c) * 2048 + pos] = (_Float16)acc[mt][nt][i];
        }
    }
  }
}

// ---------------- flash attention, swapped QK^T, no LDS ----------------
// 1 wave = 32 q rows of one (b,h). S^T = mfma(K,Q); P stays in C-regs for PV.
__global__ __launch_bounds__(256) void attn_k(const _Float16* __restrict__ qn,
                                              const _Float16* __restrict__ kn,
                                              const _Float16* __restrict__ vt,
                                              _Float16* __restrict__ ao) {
  const int tid = threadIdx.x;
  const int wid = tid >> 6;
  const int l31 = tid & 31;
  const int hi = (tid >> 5) & 1;
  // XCD swizzle: 16 blocks (=1 head... 8 heads) per XCD for K/V L2 residency
  const int dd = blockIdx.x;
  const int xcd = dd & 7, j = dd >> 3;
  const int bh = xcd * 8 + (j >> 4);
  const int qg = j & 15;
  const int qt = (qg << 2) | wid;
  const int q = (qt << 5) | l31;
  const int b = bh >> 5, h = bh & 31;

  const _Float16* qrow = qn + ((size_t)bh * 2048 + q) * 64;
  h8 qf[4];
#pragma unroll
  for (int dc = 0; dc < 4; ++dc) {
    h4 lo = *(const h4*)(qrow + dc * 16 + 4 * hi);
    h4 h2 = *(const h4*)(qrow + dc * 16 + 8 + 4 * hi);
    qf[dc] = __builtin_shufflevector(lo, h2, 0, 1, 2, 3, 4, 5, 6, 7);
  }

  const _Float16* kb = kn + (size_t)bh * 2048 * 64;
  const _Float16* vb = vt + (size_t)bh * 64 * 2048;

  f32x16 acc0, acc1;
#pragma unroll
  for (int e = 0; e < 16; ++e) { acc0[e] = 0.f; acc1[e] = 0.f; }
  float lsum = 0.f;

  for (int kv0 = 0; kv0 < 2048; kv0 += 32) {
    const _Float16* krow = kb + (size_t)(kv0 + l31) * 64;
    f32x16 S;
#pragma unroll
    for (int e = 0; e < 16; ++e) S[e] = 0.f;
#pragma unroll
    for (int dc = 0; dc < 4; ++dc) {
      h4 lo = *(const h4*)(krow + dc * 16 + 4 * hi);
      h4 h2 = *(const h4*)(krow + dc * 16 + 8 + 4 * hi);
      h8 kf = __builtin_shufflevector(lo, h2, 0, 1, 2, 3, 4, 5, 6, 7);
      S = __builtin_amdgcn_mfma_f32_32x32x16_f16(kf, qf[dc], S, 0, 0, 0);
    }
    // scores bounded: |S|<=1 (unit q,k), scale 1/8 -> exp safe without max-subtract
    float p[16];
#pragma unroll
    for (int e = 0; e < 16; ++e) { p[e] = __expf(S[e] * 0.125f); lsum += p[e]; }
    h8 pb0, pb1;
#pragma unroll
    for (int e = 0; e < 8; ++e) { pb0[e] = (_Float16)p[e]; pb1[e] = (_Float16)p[e + 8]; }
#pragma unroll
    for (int dta = 0; dta < 2; ++dta) {
      const _Float16* vrow = vb + (size_t)(dta * 32 + l31) * 2048 + kv0;
      h4 a0 = *(const h4*)(vrow + 4 * hi);
      h4 a1 = *(const h4*)(vrow + 8 + 4 * hi);
      h8 vf0 = __builtin_shufflevector(a0, a1, 0, 1, 2, 3, 4, 5, 6, 7);
      h4 a2 = *(const h4*)(vrow + 16 + 4 * hi);
      h4 a3 = *(const h4*)(vrow + 24 + 4 * hi);
      h8 vf1 = __builtin_shufflevector(a2, a3, 0, 1, 2, 3, 4, 5, 6, 7);
      if (dta == 0) {
        acc0 = __builtin_amdgcn_mfma_f32_32x32x16_f16(vf0, pb0, acc0, 0, 0, 0);
        acc0 = __builtin_amdgcn_mfma_f32_32x32x16_f16(vf1, pb1, acc0, 0, 0, 0);
      } else {
        acc1 = __builtin_amdgcn_mfma_f32_32x32x16_f16(vf0, pb0, acc1, 0, 0, 0);
        acc1 = __builtin_amdgcn_mfma_f32_32x32x16_f16(vf1, pb1, acc1, 0, 0, 0);
      }
    }
  }
  lsum += __shfl_xor(lsum, 32);
  const float inv = 1.0f / lsum;
  _Float16* orow = ao + ((size_t)b * 2048 + q) * 2048 + h * 64;
#pragma unroll
  for (int dta = 0; dta < 2; ++dta) {
#pragma unroll
    for (int blk = 0; blk < 4; ++blk) {
      h4 st;
#pragma unroll
      for (int e = 0; e < 4; ++e) {
        const float v = (dta == 0) ? acc0[blk * 4 + e] : acc1[blk * 4 + e];
        st[e] = (_Float16)(v * inv);
      }
      *(h4*)(orow + dta * 32 + blk * 8 + 4 * hi) = st;
    }
  }
}

extern "C" void kernel_launch(void* const* d_in, const int* in_sizes, int n_in,
                              void* d_out, int out_size, void* d_ws, size_t ws_size,
                              hipStream_t stream) {
  const float* x = (const float*)d_in[0];
  const float* wqkv = (const float*)d_in[1];
  const float* wout = (const float*)d_in[2];
  const float* freqs = (const float*)d_in[3];
  char* ws = (char*)d_ws;
  _Float16* xb    = (_Float16*)ws;                          // 16 MB
  _Float16* attno = xb;                                     // alias: x dead after gemm1
  _Float16* wqkvT = (_Float16*)(ws + (size_t)(16 << 20));   // 24 MB
  _Float16* woutT = (_Float16*)(ws + (size_t)(40 << 20));   // 8 MB
  _Float16* qn    = (_Float16*)(ws + (size_t)(48 << 20));   // 16 MB
  _Float16* kn    = (_Float16*)(ws + (size_t)(64 << 20));   // 16 MB
  _Float16* vT    = (_Float16*)(ws + (size_t)(80 << 20));   // 16 MB  (total 96 MB)
  float* out = (float*)d_out;

  convk<<<8192, 256, 0, stream>>>(x, xb, 2 * 2048 * 2048);
  transconv_k<<<(6144 / 64) * (2048 / 64), 256, 0, stream>>>(wqkv, wqkvT, 2048, 6144);
  transconv_k<<<(2048 / 64) * (2048 / 64), 256, 0, stream>>>(wout, woutT, 2048, 2048);
  gemm_k<1><<<48 * 32, 256, 0, stream>>>(xb, wqkvT, 2048, 48, qn, kn, vT, freqs, nullptr);
  attn_k<<<1024, 256, 0, stream>>>(qn, kn, vT, attno);
  gemm_k<0><<<16 * 32, 256, 0, stream>>>(attno, woutT, 2048, 16, nullptr, nullptr, nullptr,
                                         nullptr, out);
}

// Round 2
// 758.674 us; speedup vs baseline: 1.2754x; 1.2754x over previous
//
#include <hip/hip_runtime.h>
#include <cstdint>

typedef _Float16 h4 __attribute__((ext_vector_type(4)));
typedef _Float16 h8 __attribute__((ext_vector_type(8)));
typedef float f32x4 __attribute__((ext_vector_type(4)));
typedef float f32x16 __attribute__((ext_vector_type(16)));

// ---------- async global->LDS, 16B per lane, wave-uniform LDS base ----------
__device__ __forceinline__ void g2l16(const void* g, void* l) {
  __builtin_amdgcn_global_load_lds(
      (__attribute__((address_space(1))) void*)(uintptr_t)(g),
      (__attribute__((address_space(3))) void*)(l), 16, 0, 0);
}

// A/B fragment for mfma_*_x32 (BK=32 chunk): k(g,j) = 4g+j (j0..3), 16+4g+(j-4) (j4..7)
__device__ __forceinline__ h8 frag16(const _Float16* row, int g) {
  h4 lo = *(const h4*)(row + 4 * g);
  h4 hi = *(const h4*)(row + 16 + 4 * g);
  return __builtin_shufflevector(lo, hi, 0, 1, 2, 3, 4, 5, 6, 7);
}

// ---------------- fp32 -> fp16 elementwise ----------------
__global__ __launch_bounds__(256) void convk(const float* __restrict__ in,
                                             _Float16* __restrict__ out, int n) {
  int i = (blockIdx.x * 256 + threadIdx.x) * 4;
  if (i + 3 < n) {
    const float4 v = *(const float4*)(in + i);
    h4 o;
    o[0] = (_Float16)v.x; o[1] = (_Float16)v.y; o[2] = (_Float16)v.z; o[3] = (_Float16)v.w;
    *(h4*)(out + i) = o;
  }
}

// ---------------- fp32 [R][C] -> fp16 [C][R] transpose-convert ----------------
__global__ __launch_bounds__(256) void transconv_k(const float* __restrict__ in,
                                                   _Float16* __restrict__ out,
                                                   int R, int C) {
  __shared__ float tile[64][65];
  const int tC = C >> 6;
  const int bc = blockIdx.x % tC, br = blockIdx.x / tC;
  const int r0 = br << 6, c0 = bc << 6;
  const int t = threadIdx.x;
  const int lr = t >> 4, lc = (t & 15) << 2;
#pragma unroll
  for (int p = 0; p < 4; ++p) {
    const float4 v = *(const float4*)(in + (size_t)(r0 + p * 16 + lr) * C + c0 + lc);
    tile[p * 16 + lr][lc + 0] = v.x;
    tile[p * 16 + lr][lc + 1] = v.y;
    tile[p * 16 + lr][lc + 2] = v.z;
    tile[p * 16 + lr][lc + 3] = v.w;
  }
  __syncthreads();
#pragma unroll
  for (int p = 0; p < 4; ++p) {
    const int oc = p * 16 + lr;  // out-row = in-col
    h4 v;
#pragma unroll
    for (int e = 0; e < 4; ++e) v[e] = (_Float16)tile[lc + e][oc];
    *(h4*)(out + (size_t)(c0 + oc) * R + r0 + lc) = v;
  }
}

// ---------------- GEMM: C[M][N] = A[M][K] * BT[N][K]^T  (fp16 in, fp32 acc) ----------------
// MODE 0: plain fp32 store to fo (N = NTILES*128)
// MODE 1: QKV epilogue: l2norm + rope -> outq/outk [bh][n][64]; v -> outv [bh][64][n] with
//         kv-index bits 2<->3 swapped so attn's V fragment loads are contiguous 16B.
template <int MODE>
__global__ __launch_bounds__(256) void gemm_k(
    const _Float16* __restrict__ A, const _Float16* __restrict__ BT,
    const int K, const int NTILES,
    _Float16* __restrict__ outq, _Float16* __restrict__ outk,
    _Float16* __restrict__ outv, const float* __restrict__ freqs,
    float* __restrict__ fo) {
  __shared__ __align__(16) _Float16 As[128 * 32];
  __shared__ __align__(16) _Float16 Bs[128 * 32];
  const int tid = threadIdx.x;
  const int bt = blockIdx.x % NTILES;
  const int mb = blockIdx.x / NTILES;
  const int m0 = mb * 128, n0 = bt * 128;
  const int wid = tid >> 6, lane = tid & 63;
  const int wr = wid >> 1, wc = wid & 1;
  const int g = lane >> 4, c = lane & 15;

  f32x4 acc[4][4];
#pragma unroll
  for (int i = 0; i < 4; ++i)
#pragma unroll
    for (int j = 0; j < 4; ++j)
#pragma unroll
      for (int e = 0; e < 4; ++e) acc[i][j][e] = 0.f;

  const int ldr = tid >> 2;
  const int lko = (tid & 3) * 8;
  const _Float16* ag = A + (size_t)(m0 + ldr) * K + lko;
  const _Float16* bg = BT + (size_t)(n0 + ldr) * K + lko;
  _Float16* asw = As + wid * 512;
  _Float16* bsw = Bs + wid * 512;
  const size_t rowhop = (size_t)64 * K;

  const int nk = K >> 5;
  for (int kt = 0; kt < nk; ++kt) {
    __syncthreads();  // previous tile fully consumed
    const int kof = kt << 5;
    g2l16(ag + kof, asw);
    g2l16(ag + rowhop + kof, asw + 2048);
    g2l16(bg + kof, bsw);
    g2l16(bg + rowhop + kof, bsw + 2048);
    __syncthreads();  // staging drained (vmcnt(0) before barrier)
    h8 af[4], bf[4];
#pragma unroll
    for (int t = 0; t < 4; ++t) af[t] = frag16(As + (wr * 64 + t * 16 + c) * 32, g);
#pragma unroll
    for (int t = 0; t < 4; ++t) bf[t] = frag16(Bs + (wc * 64 + t * 16 + c) * 32, g);
#pragma unroll
    for (int i = 0; i < 4; ++i)
#pragma unroll
      for (int j = 0; j < 4; ++j)
        acc[i][j] = __builtin_amdgcn_mfma_f32_16x16x32_f16(af[i], bf[j], acc[i][j], 0, 0, 0);
  }

  if (MODE == 0) {
    const int Ncols = NTILES * 128;
#pragma unroll
    for (int mt = 0; mt < 4; ++mt)
#pragma unroll
      for (int i = 0; i < 4; ++i) {
        const int m = m0 + wr * 64 + mt * 16 + 4 * g + i;
        float* orow = fo + (size_t)m * Ncols + n0 + wc * 64 + c;
#pragma unroll
        for (int nt = 0; nt < 4; ++nt) orow[nt * 16] = acc[mt][nt][i];
      }
  } else {
    const int hh = ((bt & 15) << 1) | wc;  // head 0..31 within its third
    const int third = bt >> 4;             // 0=q 1=k 2=v
    if (third < 2) {
      _Float16* dst0 = (third == 0) ? outq : outk;
#pragma unroll
      for (int mt = 0; mt < 4; ++mt) {
        float ss[4];
#pragma unroll
        for (int i = 0; i < 4; ++i) {
          float s = 0.f;
#pragma unroll
          for (int nt = 0; nt < 4; ++nt) { const float v = acc[mt][nt][i]; s += v * v; }
          ss[i] = s;
        }
#pragma unroll
        for (int msk = 1; msk < 16; msk <<= 1)
#pragma unroll
          for (int i = 0; i < 4; ++i) ss[i] += __shfl_xor(ss[i], msk);
#pragma unroll
        for (int i = 0; i < 4; ++i) {
          const int m = m0 + wr * 64 + mt * 16 + 4 * g + i;
          const int b = m >> 11, pos = m & 2047;
          const float inv = 1.0f / fmaxf(sqrtf(ss[i]), 1e-12f);
          const float v0 = acc[mt][0][i] * inv, v1 = acc[mt][1][i] * inv;
          const float v2 = acc[mt][2][i] * inv, v3 = acc[mt][3][i] * inv;
          float sn, cs;
          __sincosf(freqs[pos * 32 + c], &sn, &cs);
          _Float16* d = dst0 + (((size_t)((b << 5) | hh) * 2048 + pos) << 6);
          d[c]      = (_Float16)(v0 * cs - v1 * sn);
          d[16 + c] = (_Float16)(v1 * cs + v0 * sn);
          d[32 + c] = (_Float16)v2;
          d[48 + c] = (_Float16)v3;
        }
      }
    } else {
#pragma unroll
      for (int mt = 0; mt < 4; ++mt)
#pragma unroll
        for (int i = 0; i < 4; ++i) {
          const int m = m0 + wr * 64 + mt * 16 + 4 * g + i;
          const int b = m >> 11, pos = m & 2047;
          // swap bits 2<->3 of kv index: makes attn's V fragment reads contiguous
          const int posP = (pos & ~12) | ((pos & 4) << 1) | ((pos & 8) >> 1);
          const size_t hb = (size_t)((b << 5) | hh) * 64;
#pragma unroll
          for (int nt = 0; nt < 4; ++nt)
            outv[(hb + nt * 16 + c) * 2048 + posP] = (_Float16)acc[mt][nt][i];
        }
    }
  }
}

// ---------------- flash attention, swapped QK^T, no LDS, kv-split x2 ----------------
// 1 wave = 32 q rows of one (b,h), half the kv range. S^T = mfma(K,Q); P stays in
// C-regs for PV. Writes UNNORMALIZED partial O (fp16) + partial lsum (f32).
__global__ __launch_bounds__(256) void attn_k(const _Float16* __restrict__ qn,
                                              const _Float16* __restrict__ kn,
                                              const _Float16* __restrict__ vt,
                                              _Float16* __restrict__ pO,
                                              float* __restrict__ lsums) {
  const int tid = threadIdx.x;
  const int wid = tid >> 6;
  const int l31 = tid & 31;
  const int hi = (tid >> 5) & 1;
  // XCD swizzle: 16 consecutive blocks (one (bh,split)) per XCD for K/V L2 residency
  const int dd = blockIdx.x;
  const int xcd = dd & 7, j = dd >> 3;
  const int id = xcd * 16 + (j >> 4);  // (bh,split) id in [0,128)
  const int bh = id >> 1, s = id & 1;
  const int qg = j & 15;
  const int q = ((qg << 2) | wid) * 32 + l31;

  const _Float16* qrow = qn + ((size_t)bh * 2048 + q) * 64;
  h8 qf[4];
#pragma unroll
  for (int dc = 0; dc < 4; ++dc) qf[dc] = *(const h8*)(qrow + dc * 16 + 8 * hi);

  const _Float16* kb = kn + (size_t)bh * 2048 * 64 + (size_t)s * 1024 * 64;
  const _Float16* vb = vt + (size_t)bh * 64 * 2048 + s * 1024;
  const _Float16* vr0 = vb + (size_t)l31 * 2048;
  const _Float16* vr1 = vb + (size_t)(32 + l31) * 2048;

  f32x16 acc0, acc1;
#pragma unroll
  for (int e = 0; e < 16; ++e) { acc0[e] = 0.f; acc1[e] = 0.f; }
  float lsum = 0.f;
  const float C = 0.125f * 1.44269504089f;  // scale folded into exp2

  for (int kv0 = 0; kv0 < 1024; kv0 += 32) {
    const _Float16* krow = kb + (size_t)(kv0 + l31) * 64;
    h8 kf0 = *(const h8*)(krow + 8 * hi);
    h8 kf1 = *(const h8*)(krow + 16 + 8 * hi);
    h8 kf2 = *(const h8*)(krow + 32 + 8 * hi);
    h8 kf3 = *(const h8*)(krow + 48 + 8 * hi);
    // V loads issued early (independent of QK/exp)
    h8 va0 = *(const h8*)(vr0 + kv0 + 8 * hi);
    h8 va1 = *(const h8*)(vr0 + kv0 + 16 + 8 * hi);
    h8 vb0 = *(const h8*)(vr1 + kv0 + 8 * hi);
    h8 vb1 = *(const h8*)(vr1 + kv0 + 16 + 8 * hi);

    f32x16 S;
#pragma unroll
    for (int e = 0; e < 16; ++e) S[e] = 0.f;
    S = __builtin_amdgcn_mfma_f32_32x32x16_f16(kf0, qf[0], S, 0, 0, 0);
    S = __builtin_amdgcn_mfma_f32_32x32x16_f16(kf1, qf[1], S, 0, 0, 0);
    S = __builtin_amdgcn_mfma_f32_32x32x16_f16(kf2, qf[2], S, 0, 0, 0);
    S = __builtin_amdgcn_mfma_f32_32x32x16_f16(kf3, qf[3], S, 0, 0, 0);

    // |S|<=1 (unit q,k): exp2 safe without max-subtract
    float p[16];
#pragma unroll
    for (int e = 0; e < 16; ++e) { p[e] = exp2f(S[e] * C); lsum += p[e]; }
    h8 pb0, pb1;
#pragma unroll
    for (int e = 0; e < 8; ++e) { pb0[e] = (_Float16)p[e]; pb1[e] = (_Float16)p[e + 8]; }

    acc0 = __builtin_amdgcn_mfma_f32_32x32x16_f16(va0, pb0, acc0, 0, 0, 0);
    acc0 = __builtin_amdgcn_mfma_f32_32x32x16_f16(va1, pb1, acc0, 0, 0, 0);
    acc1 = __builtin_amdgcn_mfma_f32_32x32x16_f16(vb0, pb0, acc1, 0, 0, 0);
    acc1 = __builtin_amdgcn_mfma_f32_32x32x16_f16(vb1, pb1, acc1, 0, 0, 0);
  }

  lsum += __shfl_xor(lsum, 32);
  if (!(tid & 32)) lsums[(size_t)s * 131072 + (size_t)bh * 2048 + q] = lsum;

  _Float16* orow = pO + (size_t)s * 8388608 + ((size_t)bh * 2048 + q) * 64;
#pragma unroll
  for (int dta = 0; dta < 2; ++dta) {
#pragma unroll
    for (int blk = 0; blk < 4; ++blk) {
      h4 st;
#pragma unroll
      for (int e = 0; e < 4; ++e) {
        const float v = (dta == 0) ? acc0[blk * 4 + e] : acc1[blk * 4 + e];
        st[e] = (_Float16)v;
      }
      *(h4*)(orow + dta * 32 + blk * 8 + 4 * hi) = st;
    }
  }
}

// ---------------- combine partials: attno[b][q][h*64+d] = (p0+p1)/(l0+l1) ----------------
__global__ __launch_bounds__(256) void combine_k(const _Float16* __restrict__ pO,
                                                 const float* __restrict__ lsums,
                                                 _Float16* __restrict__ attno) {
  const int idx = blockIdx.x * 256 + threadIdx.x;
  const int row = idx >> 3;           // bh*2048 + q, in [0, 131072)
  const int dpart = (idx & 7) * 8;
  const int bh = row >> 11, q = row & 2047;
  const float inv = 1.0f / (lsums[row] + lsums[131072 + row]);
  const h8 a = *(const h8*)(pO + (size_t)row * 64 + dpart);
  const h8 b = *(const h8*)(pO + 8388608 + (size_t)row * 64 + dpart);
  h8 o;
#pragma unroll
  for (int e = 0; e < 8; ++e) o[e] = (_Float16)(((float)a[e] + (float)b[e]) * inv);
  const int bb = bh >> 5, h = bh & 31;
  *(h8*)(attno + ((size_t)bb * 2048 + q) * 2048 + h * 64 + dpart) = o;
}

extern "C" void kernel_launch(void* const* d_in, const int* in_sizes, int n_in,
                              void* d_out, int out_size, void* d_ws, size_t ws_size,
                              hipStream_t stream) {
  const float* x = (const float*)d_in[0];
  const float* wqkv = (const float*)d_in[1];
  const float* wout = (const float*)d_in[2];
  const float* freqs = (const float*)d_in[3];
  char* ws = (char*)d_ws;
  _Float16* xb    = (_Float16*)ws;                          // [0,16M)  gemm1 A input
  _Float16* pO    = xb;                                     // [0,32M)  attn partials (x/wqkvT dead)
  _Float16* wqkvT = (_Float16*)(ws + (size_t)(16 << 20));   // [16,40M) gemm1 B input
  float*    lsums = (float*)(ws + (size_t)(32 << 20));      // [32,33M) partial lsums
  _Float16* woutT = (_Float16*)(ws + (size_t)(40 << 20));   // [40,48M)
  _Float16* qn    = (_Float16*)(ws + (size_t)(48 << 20));   // [48,64M) q; attno after attn
  _Float16* attno = qn;                                     //          (q dead after attn)
  _Float16* kn    = (_Float16*)(ws + (size_t)(64 << 20));   // [64,80M)
  _Float16* vT    = (_Float16*)(ws + (size_t)(80 << 20));   // [80,96M)
  float* out = (float*)d_out;

  convk<<<8192, 256, 0, stream>>>(x, xb, 2 * 2048 * 2048);
  transconv_k<<<(6144 / 64) * (2048 / 64), 256, 0, stream>>>(wqkv, wqkvT, 2048, 6144);
  transconv_k<<<(2048 / 64) * (2048 / 64), 256, 0, stream>>>(wout, woutT, 2048, 2048);
  gemm_k<1><<<48 * 32, 256, 0, stream>>>(xb, wqkvT, 2048, 48, qn, kn, vT, freqs, nullptr);
  attn_k<<<2048, 256, 0, stream>>>(qn, kn, vT, pO, lsums);
  combine_k<<<4096, 256, 0, stream>>>(pO, lsums, attno);
  gemm_k<0><<<16 * 32, 256, 0, stream>>>(attno, woutT, 2048, 16, nullptr, nullptr, nullptr,
                                         nullptr, out);
}

// Round 3
// 485.030 us; speedup vs baseline: 1.9950x; 1.5642x over previous
//
#include <hip/hip_runtime.h>
#include <cstdint>

typedef _Float16 h4 __attribute__((ext_vector_type(4)));
typedef _Float16 h8 __attribute__((ext_vector_type(8)));
typedef float f32x4 __attribute__((ext_vector_type(4)));
typedef float f32x16 __attribute__((ext_vector_type(16)));

// ---------- async global->LDS, 16B per lane, wave-uniform LDS base ----------
__device__ __forceinline__ void g2l16(const void* g, void* l) {
  __builtin_amdgcn_global_load_lds(
      (__attribute__((address_space(1))) void*)(uintptr_t)(g),
      (__attribute__((address_space(3))) void*)(l), 16, 0, 0);
}

// ---------------- fp32 -> fp16 elementwise ----------------
__global__ __launch_bounds__(256) void convk(const float* __restrict__ in,
                                             _Float16* __restrict__ out, int n) {
  int i = (blockIdx.x * 256 + threadIdx.x) * 4;
  if (i + 3 < n) {
    const float4 v = *(const float4*)(in + i);
    h4 o;
    o[0] = (_Float16)v.x; o[1] = (_Float16)v.y; o[2] = (_Float16)v.z; o[3] = (_Float16)v.w;
    *(h4*)(out + i) = o;
  }
}

// ---------------- fp32 [R][C] -> fp16 [C][R] transpose-convert ----------------
__global__ __launch_bounds__(256) void transconv_k(const float* __restrict__ in,
                                                   _Float16* __restrict__ out,
                                                   int R, int C) {
  __shared__ float tile[64][65];
  const int tC = C >> 6;
  const int bc = blockIdx.x % tC, br = blockIdx.x / tC;
  const int r0 = br << 6, c0 = bc << 6;
  const int t = threadIdx.x;
  const int lr = t >> 4, lc = (t & 15) << 2;
#pragma unroll
  for (int p = 0; p < 4; ++p) {
    const float4 v = *(const float4*)(in + (size_t)(r0 + p * 16 + lr) * C + c0 + lc);
    tile[p * 16 + lr][lc + 0] = v.x;
    tile[p * 16 + lr][lc + 1] = v.y;
    tile[p * 16 + lr][lc + 2] = v.z;
    tile[p * 16 + lr][lc + 3] = v.w;
  }
  __syncthreads();
#pragma unroll
  for (int p = 0; p < 4; ++p) {
    const int oc = p * 16 + lr;  // out-row = in-col
    h4 v;
#pragma unroll
    for (int e = 0; e < 4; ++e) v[e] = (_Float16)tile[lc + e][oc];
    *(h4*)(out + (size_t)(c0 + oc) * R + r0 + lc) = v;
  }
}

// ---------------- GEMM: C[M][N] = A[M][K] * BT[N][K]^T  (fp16 in, fp32 acc) ----------------
// k-fragment mapping: contiguous k(g,j)=8g+j for BOTH A and B (consistent bijection ==
// correct for any true HW k-map). One aligned ds_read_b128 per fragment; bank-group
// 4*(row&1)+g covers all 8 groups x 8 lanes -> conflict-free.
// MODE 0: plain fp32 store to fo (N = NTILES*128)
// MODE 1: QKV epilogue: l2norm + rope -> outq/outk [bh][n][64]; v -> outv [bh][64][n] with
//         kv-index bits 2<->3 swapped so attn's V fragment loads are contiguous 16B.
template <int MODE>
__global__ __launch_bounds__(256) void gemm_k(
    const _Float16* __restrict__ A, const _Float16* __restrict__ BT,
    const int K, const int NTILES,
    _Float16* __restrict__ outq, _Float16* __restrict__ outk,
    _Float16* __restrict__ outv, const float* __restrict__ freqs,
    float* __restrict__ fo) {
  __shared__ __align__(16) _Float16 As[128 * 32];
  __shared__ __align__(16) _Float16 Bs[128 * 32];
  const int tid = threadIdx.x;
  // bijective XCD-chunk swizzle (gridDim.x % 8 == 0): each XCD gets a contiguous range
  const int cpx = gridDim.x >> 3;
  const int nb = (blockIdx.x & 7) * cpx + (blockIdx.x >> 3);
  const int bt = nb % NTILES;
  const int mb = nb / NTILES;
  const int m0 = mb * 128, n0 = bt * 128;
  const int wid = tid >> 6, lane = tid & 63;
  const int wr = wid >> 1, wc = wid & 1;
  const int g = lane >> 4, c = lane & 15;

  f32x4 acc[4][4];
#pragma unroll
  for (int i = 0; i < 4; ++i)
#pragma unroll
    for (int j = 0; j < 4; ++j)
#pragma unroll
      for (int e = 0; e < 4; ++e) acc[i][j][e] = 0.f;

  const int ldr = tid >> 2;
  const int lko = (tid & 3) * 8;
  const _Float16* ag = A + (size_t)(m0 + ldr) * K + lko;
  const _Float16* bg = BT + (size_t)(n0 + ldr) * K + lko;
  _Float16* asw = As + wid * 512;
  _Float16* bsw = Bs + wid * 512;
  const size_t rowhop = (size_t)64 * K;

  const int nk = K >> 5;
  for (int kt = 0; kt < nk; ++kt) {
    __syncthreads();  // previous tile fully consumed
    const int kof = kt << 5;
    g2l16(ag + kof, asw);
    g2l16(ag + rowhop + kof, asw + 2048);
    g2l16(bg + kof, bsw);
    g2l16(bg + rowhop + kof, bsw + 2048);
    __syncthreads();  // staging drained (vmcnt(0) before barrier)
    h8 af[4], bf[4];
#pragma unroll
    for (int t = 0; t < 4; ++t) af[t] = *(const h8*)(As + (wr * 64 + t * 16 + c) * 32 + 8 * g);
#pragma unroll
    for (int t = 0; t < 4; ++t) bf[t] = *(const h8*)(Bs + (wc * 64 + t * 16 + c) * 32 + 8 * g);
#pragma unroll
    for (int i = 0; i < 4; ++i)
#pragma unroll
      for (int j = 0; j < 4; ++j)
        acc[i][j] = __builtin_amdgcn_mfma_f32_16x16x32_f16(af[i], bf[j], acc[i][j], 0, 0, 0);
  }

  if (MODE == 0) {
    const int Ncols = NTILES * 128;
#pragma unroll
    for (int mt = 0; mt < 4; ++mt)
#pragma unroll
      for (int i = 0; i < 4; ++i) {
        const int m = m0 + wr * 64 + mt * 16 + 4 * g + i;
        float* orow = fo + (size_t)m * Ncols + n0 + wc * 64 + c;
#pragma unroll
        for (int nt = 0; nt < 4; ++nt) orow[nt * 16] = acc[mt][nt][i];
      }
  } else {
    const int hh = ((bt & 15) << 1) | wc;  // head 0..31 within its third
    const int third = bt >> 4;             // 0=q 1=k 2=v
    if (third < 2) {
      _Float16* dst0 = (third == 0) ? outq : outk;
#pragma unroll
      for (int mt = 0; mt < 4; ++mt) {
        float ss[4];
#pragma unroll
        for (int i = 0; i < 4; ++i) {
          float s = 0.f;
#pragma unroll
          for (int nt = 0; nt < 4; ++nt) { const float v = acc[mt][nt][i]; s += v * v; }
          ss[i] = s;
        }
#pragma unroll
        for (int msk = 1; msk < 16; msk <<= 1)
#pragma unroll
          for (int i = 0; i < 4; ++i) ss[i] += __shfl_xor(ss[i], msk);
#pragma unroll
        for (int i = 0; i < 4; ++i) {
          const int m = m0 + wr * 64 + mt * 16 + 4 * g + i;
          const int b = m >> 11, pos = m & 2047;
          const float inv = 1.0f / fmaxf(sqrtf(ss[i]), 1e-12f);
          const float v0 = acc[mt][0][i] * inv, v1 = acc[mt][1][i] * inv;
          const float v2 = acc[mt][2][i] * inv, v3 = acc[mt][3][i] * inv;
          float sn, cs;
          __sincosf(freqs[pos * 32 + c], &sn, &cs);
          _Float16* d = dst0 + (((size_t)((b << 5) | hh) * 2048 + pos) << 6);
          d[c]      = (_Float16)(v0 * cs - v1 * sn);
          d[16 + c] = (_Float16)(v1 * cs + v0 * sn);
          d[32 + c] = (_Float16)v2;
          d[48 + c] = (_Float16)v3;
        }
      }
    } else {
#pragma unroll
      for (int mt = 0; mt < 4; ++mt)
#pragma unroll
        for (int i = 0; i < 4; ++i) {
          const int m = m0 + wr * 64 + mt * 16 + 4 * g + i;
          const int b = m >> 11, pos = m & 2047;
          // swap bits 2<->3 of kv index: makes attn's V fragment reads contiguous
          const int posP = (pos & ~12) | ((pos & 4) << 1) | ((pos & 8) >> 1);
          const size_t hb = (size_t)((b << 5) | hh) * 64;
#pragma unroll
          for (int nt = 0; nt < 4; ++nt)
            outv[(hb + nt * 16 + c) * 2048 + posP] = (_Float16)acc[mt][nt][i];
        }
    }
  }
}

// ---------------- flash attention, swapped QK^T, no LDS, kv-split x2 ----------------
// 1 wave = 32 q rows of one (b,h), half the kv range. S^T = mfma(K,Q); P stays in
// C-regs for PV. Writes UNNORMALIZED partial O (fp16) + partial lsum (f32).
__global__ __launch_bounds__(256) void attn_k(const _Float16* __restrict__ qn,
                                              const _Float16* __restrict__ kn,
                                              const _Float16* __restrict__ vt,
                                              _Float16* __restrict__ pO,
                                              float* __restrict__ lsums) {
  const int tid = threadIdx.x;
  const int wid = tid >> 6;
  const int l31 = tid & 31;
  const int hi = (tid >> 5) & 1;
  // XCD swizzle: 16 consecutive blocks (one (bh,split)) per XCD for K/V L2 residency
  const int dd = blockIdx.x;
  const int xcd = dd & 7, j = dd >> 3;
  const int id = xcd * 16 + (j >> 4);  // (bh,split) id in [0,128)
  const int bh = id >> 1, s = id & 1;
  const int qg = j & 15;
  const int q = ((qg << 2) | wid) * 32 + l31;

  const _Float16* qrow = qn + ((size_t)bh * 2048 + q) * 64;
  h8 qf[4];
#pragma unroll
  for (int dc = 0; dc < 4; ++dc) qf[dc] = *(const h8*)(qrow + dc * 16 + 8 * hi);

  const _Float16* kb = kn + (size_t)bh * 2048 * 64 + (size_t)s * 1024 * 64;
  const _Float16* vb = vt + (size_t)bh * 64 * 2048 + s * 1024;
  const _Float16* vr0 = vb + (size_t)l31 * 2048;
  const _Float16* vr1 = vb + (size_t)(32 + l31) * 2048;

  f32x16 acc0, acc1;
#pragma unroll
  for (int e = 0; e < 16; ++e) { acc0[e] = 0.f; acc1[e] = 0.f; }
  float lsum = 0.f;
  const float C = 0.125f * 1.44269504089f;  // scale folded into exp2

  for (int kv0 = 0; kv0 < 1024; kv0 += 32) {
    const _Float16* krow = kb + (size_t)(kv0 + l31) * 64;
    h8 kf0 = *(const h8*)(krow + 8 * hi);
    h8 kf1 = *(const h8*)(krow + 16 + 8 * hi);
    h8 kf2 = *(const h8*)(krow + 32 + 8 * hi);
    h8 kf3 = *(const h8*)(krow + 48 + 8 * hi);
    // V loads issued early (independent of QK/exp)
    h8 va0 = *(const h8*)(vr0 + kv0 + 8 * hi);
    h8 va1 = *(const h8*)(vr0 + kv0 + 16 + 8 * hi);
    h8 vb0 = *(const h8*)(vr1 + kv0 + 8 * hi);
    h8 vb1 = *(const h8*)(vr1 + kv0 + 16 + 8 * hi);

    f32x16 S;
#pragma unroll
    for (int e = 0; e < 16; ++e) S[e] = 0.f;
    S = __builtin_amdgcn_mfma_f32_32x32x16_f16(kf0, qf[0], S, 0, 0, 0);
    S = __builtin_amdgcn_mfma_f32_32x32x16_f16(kf1, qf[1], S, 0, 0, 0);
    S = __builtin_amdgcn_mfma_f32_32x32x16_f16(kf2, qf[2], S, 0, 0, 0);
    S = __builtin_amdgcn_mfma_f32_32x32x16_f16(kf3, qf[3], S, 0, 0, 0);

    // |S|<=1 (unit q,k): exp2 safe without max-subtract
    float p[16];
#pragma unroll
    for (int e = 0; e < 16; ++e) { p[e] = exp2f(S[e] * C); lsum += p[e]; }
    h8 pb0, pb1;
#pragma unroll
    for (int e = 0; e < 8; ++e) { pb0[e] = (_Float16)p[e]; pb1[e] = (_Float16)p[e + 8]; }

    acc0 = __builtin_amdgcn_mfma_f32_32x32x16_f16(va0, pb0, acc0, 0, 0, 0);
    acc0 = __builtin_amdgcn_mfma_f32_32x32x16_f16(va1, pb1, acc0, 0, 0, 0);
    acc1 = __builtin_amdgcn_mfma_f32_32x32x16_f16(vb0, pb0, acc1, 0, 0, 0);
    acc1 = __builtin_amdgcn_mfma_f32_32x32x16_f16(vb1, pb1, acc1, 0, 0, 0);
  }

  lsum += __shfl_xor(lsum, 32);
  if (!(tid & 32)) lsums[(size_t)s * 131072 + (size_t)bh * 2048 + q] = lsum;

  _Float16* orow = pO + (size_t)s * 8388608 + ((size_t)bh * 2048 + q) * 64;
#pragma unroll
  for (int dta = 0; dta < 2; ++dta) {
#pragma unroll
    for (int blk = 0; blk < 4; ++blk) {
      h4 st;
#pragma unroll
      for (int e = 0; e < 4; ++e) {
        const float v = (dta == 0) ? acc0[blk * 4 + e] : acc1[blk * 4 + e];
        st[e] = (_Float16)v;
      }
      *(h4*)(orow + dta * 32 + blk * 8 + 4 * hi) = st;
    }
  }
}

// ---------------- combine partials: attno[b][q][h*64+d] = (p0+p1)/(l0+l1) ----------------
__global__ __launch_bounds__(256) void combine_k(const _Float16* __restrict__ pO,
                                                 const float* __restrict__ lsums,
                                                 _Float16* __restrict__ attno) {
  const int idx = blockIdx.x * 256 + threadIdx.x;
  const int row = idx >> 3;           // bh*2048 + q, in [0, 131072)
  const int dpart = (idx & 7) * 8;
  const int bh = row >> 11, q = row & 2047;
  const float inv = 1.0f / (lsums[row] + lsums[131072 + row]);
  const h8 a = *(const h8*)(pO + (size_t)row * 64 + dpart);
  const h8 b = *(const h8*)(pO + 8388608 + (size_t)row * 64 + dpart);
  h8 o;
#pragma unroll
  for (int e = 0; e < 8; ++e) o[e] = (_Float16)(((float)a[e] + (float)b[e]) * inv);
  const int bb = bh >> 5, h = bh & 31;
  *(h8*)(attno + ((size_t)bb * 2048 + q) * 2048 + h * 64 + dpart) = o;
}

extern "C" void kernel_launch(void* const* d_in, const int* in_sizes, int n_in,
                              void* d_out, int out_size, void* d_ws, size_t ws_size,
                              hipStream_t stream) {
  const float* x = (const float*)d_in[0];
  const float* wqkv = (const float*)d_in[1];
  const float* wout = (const float*)d_in[2];
  const float* freqs = (const float*)d_in[3];
  char* ws = (char*)d_ws;
  _Float16* xb    = (_Float16*)ws;                          // [0,16M)  gemm1 A input
  _Float16* pO    = xb;                                     // [0,32M)  attn partials (x/wqkvT dead)
  _Float16* wqkvT = (_Float16*)(ws + (size_t)(16 << 20));   // [16,40M) gemm1 B input
  float*    lsums = (float*)(ws + (size_t)(32 << 20));      // [32,33M) partial lsums
  _Float16* woutT = (_Float16*)(ws + (size_t)(40 << 20));   // [40,48M)
  _Float16* qn    = (_Float16*)(ws + (size_t)(48 << 20));   // [48,64M) q; attno after attn
  _Float16* attno = qn;                                     //          (q dead after attn)
  _Float16* kn    = (_Float16*)(ws + (size_t)(64 << 20));   // [64,80M)
  _Float16* vT    = (_Float16*)(ws + (size_t)(80 << 20));   // [80,96M)
  float* out = (float*)d_out;

  convk<<<8192, 256, 0, stream>>>(x, xb, 2 * 2048 * 2048);
  transconv_k<<<(6144 / 64) * (2048 / 64), 256, 0, stream>>>(wqkv, wqkvT, 2048, 6144);
  transconv_k<<<(2048 / 64) * (2048 / 64), 256, 0, stream>>>(wout, woutT, 2048, 2048);
  gemm_k<1><<<48 * 32, 256, 0, stream>>>(xb, wqkvT, 2048, 48, qn, kn, vT, freqs, nullptr);
  attn_k<<<2048, 256, 0, stream>>>(qn, kn, vT, pO, lsums);
  combine_k<<<4096, 256, 0, stream>>>(pO, lsums, attno);
  gemm_k<0><<<16 * 32, 256, 0, stream>>>(attno, woutT, 2048, 16, nullptr, nullptr, nullptr,
                                         nullptr, out);
}

// Round 4
// 362.172 us; speedup vs baseline: 2.6717x; 1.3392x over previous
//
#include <hip/hip_runtime.h>
#include <cstdint>

typedef _Float16 h4 __attribute__((ext_vector_type(4)));
typedef _Float16 h8 __attribute__((ext_vector_type(8)));
typedef float f32x4 __attribute__((ext_vector_type(4)));
typedef float f32x16 __attribute__((ext_vector_type(16)));

// ---------- async global->LDS, 16B per lane, wave-uniform LDS base ----------
__device__ __forceinline__ void g2l16(const void* g, void* l) {
  __builtin_amdgcn_global_load_lds(
      (__attribute__((address_space(1))) void*)(uintptr_t)(g),
      (__attribute__((address_space(3))) void*)(l), 16, 0, 0);
}

// ---------------- fp32 -> fp16 elementwise ----------------
__global__ __launch_bounds__(256) void convk(const float* __restrict__ in,
                                             _Float16* __restrict__ out, int n) {
  int i = (blockIdx.x * 256 + threadIdx.x) * 4;
  if (i + 3 < n) {
    const float4 v = *(const float4*)(in + i);
    h4 o;
    o[0] = (_Float16)v.x; o[1] = (_Float16)v.y; o[2] = (_Float16)v.z; o[3] = (_Float16)v.w;
    *(h4*)(out + i) = o;
  }
}

// ---------------- fp32 [R][C] -> fp16 [C][R] transpose-convert ----------------
__global__ __launch_bounds__(256) void transconv_k(const float* __restrict__ in,
                                                   _Float16* __restrict__ out,
                                                   int R, int C) {
  __shared__ float tile[64][65];
  const int tC = C >> 6;
  const int bc = blockIdx.x % tC, br = blockIdx.x / tC;
  const int r0 = br << 6, c0 = bc << 6;
  const int t = threadIdx.x;
  const int lr = t >> 4, lc = (t & 15) << 2;
#pragma unroll
  for (int p = 0; p < 4; ++p) {
    const float4 v = *(const float4*)(in + (size_t)(r0 + p * 16 + lr) * C + c0 + lc);
    tile[p * 16 + lr][lc + 0] = v.x;
    tile[p * 16 + lr][lc + 1] = v.y;
    tile[p * 16 + lr][lc + 2] = v.z;
    tile[p * 16 + lr][lc + 3] = v.w;
  }
  __syncthreads();
#pragma unroll
  for (int p = 0; p < 4; ++p) {
    const int oc = p * 16 + lr;  // out-row = in-col
    h4 v;
#pragma unroll
    for (int e = 0; e < 4; ++e) v[e] = (_Float16)tile[lc + e][oc];
    *(h4*)(out + (size_t)(c0 + oc) * R + r0 + lc) = v;
  }
}

// ---------------- GEMM: C[M][N] = A[M][K] * BT[N][K]^T  (fp16 in, fp32 acc) ----------------
// LDS fragment mapping k(g,j)=8g+j for BOTH A and B: one aligned ds_read_b128 per
// fragment, conflict-free.
// MODE 0: plain fp32 store to fo (N = NTILES*128)
// MODE 1: QKV epilogue: l2norm + rope; q/k/v written in attn FRAGMENT ORDER:
//   [bh][blk32][frag:4][lane:64][8 fp16]  (256KB per bh per tensor)
//   q/k: frag=dc (d-chunk of 16), lane=(d8)*32+(pos&31), elem=(d&7)
//   v:   frag=dta*2+sub, lane=(hi)*32+(d&31), elem=j with pos%16=(j&3)+8*(j>>2)+4*hi
template <int MODE>
__global__ __launch_bounds__(256) void gemm_k(
    const _Float16* __restrict__ A, const _Float16* __restrict__ BT,
    const int K, const int NTILES,
    _Float16* __restrict__ outq, _Float16* __restrict__ outk,
    _Float16* __restrict__ outv, const float* __restrict__ freqs,
    float* __restrict__ fo) {
  __shared__ __align__(16) _Float16 As[128 * 32];
  __shared__ __align__(16) _Float16 Bs[128 * 32];
  const int tid = threadIdx.x;
  // bijective XCD-chunk swizzle (gridDim.x % 8 == 0)
  const int cpx = gridDim.x >> 3;
  const int nb = (blockIdx.x & 7) * cpx + (blockIdx.x >> 3);
  const int bt = nb % NTILES;
  const int mb = nb / NTILES;
  const int m0 = mb * 128, n0 = bt * 128;
  const int wid = tid >> 6, lane = tid & 63;
  const int wr = wid >> 1, wc = wid & 1;
  const int g = lane >> 4, c = lane & 15;

  f32x4 acc[4][4];
#pragma unroll
  for (int i = 0; i < 4; ++i)
#pragma unroll
    for (int j = 0; j < 4; ++j)
#pragma unroll
      for (int e = 0; e < 4; ++e) acc[i][j][e] = 0.f;

  const int ldr = tid >> 2;
  const int lko = (tid & 3) * 8;
  const _Float16* ag = A + (size_t)(m0 + ldr) * K + lko;
  const _Float16* bg = BT + (size_t)(n0 + ldr) * K + lko;
  _Float16* asw = As + wid * 512;
  _Float16* bsw = Bs + wid * 512;
  const size_t rowhop = (size_t)64 * K;

  const int nk = K >> 5;
  for (int kt = 0; kt < nk; ++kt) {
    __syncthreads();
    const int kof = kt << 5;
    g2l16(ag + kof, asw);
    g2l16(ag + rowhop + kof, asw + 2048);
    g2l16(bg + kof, bsw);
    g2l16(bg + rowhop + kof, bsw + 2048);
    __syncthreads();
    h8 af[4], bf[4];
#pragma unroll
    for (int t = 0; t < 4; ++t) af[t] = *(const h8*)(As + (wr * 64 + t * 16 + c) * 32 + 8 * g);
#pragma unroll
    for (int t = 0; t < 4; ++t) bf[t] = *(const h8*)(Bs + (wc * 64 + t * 16 + c) * 32 + 8 * g);
#pragma unroll
    for (int i = 0; i < 4; ++i)
#pragma unroll
      for (int j = 0; j < 4; ++j)
        acc[i][j] = __builtin_amdgcn_mfma_f32_16x16x32_f16(af[i], bf[j], acc[i][j], 0, 0, 0);
  }

  if (MODE == 0) {
    const int Ncols = NTILES * 128;
#pragma unroll
    for (int mt = 0; mt < 4; ++mt)
#pragma unroll
      for (int i = 0; i < 4; ++i) {
        const int m = m0 + wr * 64 + mt * 16 + 4 * g + i;
        float* orow = fo + (size_t)m * Ncols + n0 + wc * 64 + c;
#pragma unroll
        for (int nt = 0; nt < 4; ++nt) orow[nt * 16] = acc[mt][nt][i];
      }
  } else {
    const int hh = ((bt & 15) << 1) | wc;  // head 0..31 within its third
    const int third = bt >> 4;             // 0=q 1=k 2=v
    if (third < 2) {
      _Float16* dst0 = (third == 0) ? outq : outk;
#pragma unroll
      for (int mt = 0; mt < 4; ++mt) {
        float ss[4];
#pragma unroll
        for (int i = 0; i < 4; ++i) {
          float s = 0.f;
#pragma unroll
          for (int nt = 0; nt < 4; ++nt) { const float v = acc[mt][nt][i]; s += v * v; }
          ss[i] = s;
        }
#pragma unroll
        for (int msk = 1; msk < 16; msk <<= 1)
#pragma unroll
          for (int i = 0; i < 4; ++i) ss[i] += __shfl_xor(ss[i], msk);
#pragma unroll
        for (int i = 0; i < 4; ++i) {
          const int m = m0 + wr * 64 + mt * 16 + 4 * g + i;
          const int b = m >> 11, pos = m & 2047;
          const float inv = 1.0f / fmaxf(sqrtf(ss[i]), 1e-12f);
          const float v0 = acc[mt][0][i] * inv, v1 = acc[mt][1][i] * inv;
          const float v2 = acc[mt][2][i] * inv, v3 = acc[mt][3][i] * inv;
          float sn, cs;
          __sincosf(freqs[pos * 32 + c], &sn, &cs);
          // fragment-order store: blk=pos>>5, frag=nt, lane=(c>>3)*32+(pos&31), elem=c&7
          _Float16* d = dst0 + ((size_t)((b << 5) | hh) * 64 + (pos >> 5)) * 2048 +
                        ((c >> 3) * 32 + (pos & 31)) * 8 + (c & 7);
          d[0]    = (_Float16)(v0 * cs - v1 * sn);
          d[512]  = (_Float16)(v1 * cs + v0 * sn);
          d[1024] = (_Float16)v2;
          d[1536] = (_Float16)v3;
        }
      }
    } else {
#pragma unroll
      for (int mt = 0; mt < 4; ++mt)
#pragma unroll
        for (int i = 0; i < 4; ++i) {
          const int m = m0 + wr * 64 + mt * 16 + 4 * g + i;
          const int b = m >> 11, pos = m & 2047;
          const int kvb = pos >> 5, sub = (pos >> 4) & 1, rem = pos & 15;
          const int vhi = (rem >> 2) & 1;
          const int vj = (rem & 3) + ((rem >> 3) << 2);
          const size_t hbase = ((size_t)((b << 5) | hh) * 64 + kvb) * 2048;
#pragma unroll
          for (int nt = 0; nt < 4; ++nt) {
            const int dta = nt >> 1;
            const int lfrag = vhi * 32 + (nt & 1) * 16 + c;
            outv[hbase + ((dta * 2 + sub) * 64 + lfrag) * 8 + vj] = (_Float16)acc[mt][nt][i];
          }
        }
    }
  }
}

// ---------------- flash attention, swapped QK^T, fragment-order inputs ----------------
// 1 wave = 32 q rows of one (b,h), half the kv range. All loads: base + lane*16B
// (perfectly coalesced). Writes UNNORMALIZED partial O (fp16) + partial lsum (f32).
__global__ __launch_bounds__(256) void attn_k(const _Float16* __restrict__ qf_,
                                              const _Float16* __restrict__ kf_,
                                              const _Float16* __restrict__ vf_,
                                              _Float16* __restrict__ pO,
                                              float* __restrict__ lsums) {
  const int tid = threadIdx.x;
  const int wid = tid >> 6;
  const int lane = tid & 63;
  const int l31 = tid & 31;
  // XCD swizzle: 16 consecutive blocks (one (bh,split)) per XCD for K/V L2 residency
  const int dd = blockIdx.x;
  const int xcd = dd & 7, jb = dd >> 3;
  const int id = xcd * 16 + (jb >> 4);  // (bh,split) id in [0,128)
  const int bh = id >> 1, s = id & 1;
  const int qb = ((jb & 15) << 2) | wid;  // q-block 0..63
  const int q = qb * 32 + l31;

  const _Float16* qp = qf_ + ((size_t)bh * 64 + qb) * 2048 + lane * 8;
  h8 qfr[4];
#pragma unroll
  for (int dc = 0; dc < 4; ++dc) qfr[dc] = *(const h8*)(qp + dc * 512);

  const _Float16* kp = kf_ + ((size_t)bh * 64 + s * 32) * 2048 + lane * 8;
  const _Float16* vp = vf_ + ((size_t)bh * 64 + s * 32) * 2048 + lane * 8;

  f32x16 acc0, acc1;
#pragma unroll
  for (int e = 0; e < 16; ++e) { acc0[e] = 0.f; acc1[e] = 0.f; }
  float lsum = 0.f;
  const float C = 0.125f * 1.44269504089f;  // scale folded into exp2

  for (int it = 0; it < 32; ++it) {
    const _Float16* kb = kp + it * 2048;
    const _Float16* vb = vp + it * 2048;
    h8 kf0 = *(const h8*)(kb);
    h8 kf1 = *(const h8*)(kb + 512);
    h8 kf2 = *(const h8*)(kb + 1024);
    h8 kf3 = *(const h8*)(kb + 1536);
    h8 v00 = *(const h8*)(vb);          // dta0 sub0
    h8 v01 = *(const h8*)(vb + 512);    // dta0 sub1
    h8 v10 = *(const h8*)(vb + 1024);   // dta1 sub0
    h8 v11 = *(const h8*)(vb + 1536);   // dta1 sub1

    f32x16 S;
#pragma unroll
    for (int e = 0; e < 16; ++e) S[e] = 0.f;
    S = __builtin_amdgcn_mfma_f32_32x32x16_f16(kf0, qfr[0], S, 0, 0, 0);
    S = __builtin_amdgcn_mfma_f32_32x32x16_f16(kf1, qfr[1], S, 0, 0, 0);
    S = __builtin_amdgcn_mfma_f32_32x32x16_f16(kf2, qfr[2], S, 0, 0, 0);
    S = __builtin_amdgcn_mfma_f32_32x32x16_f16(kf3, qfr[3], S, 0, 0, 0);

    // |S|<=1 (unit q,k): exp2 safe without max-subtract
    float p[16];
#pragma unroll
    for (int e = 0; e < 16; ++e) { p[e] = exp2f(S[e] * C); lsum += p[e]; }
    h8 pb0, pb1;
#pragma unroll
    for (int e = 0; e < 8; ++e) { pb0[e] = (_Float16)p[e]; pb1[e] = (_Float16)p[e + 8]; }

    acc0 = __builtin_amdgcn_mfma_f32_32x32x16_f16(v00, pb0, acc0, 0, 0, 0);
    acc0 = __builtin_amdgcn_mfma_f32_32x32x16_f16(v01, pb1, acc0, 0, 0, 0);
    acc1 = __builtin_amdgcn_mfma_f32_32x32x16_f16(v10, pb0, acc1, 0, 0, 0);
    acc1 = __builtin_amdgcn_mfma_f32_32x32x16_f16(v11, pb1, acc1, 0, 0, 0);
  }

  lsum += __shfl_xor(lsum, 32);
  if (!(tid & 32)) lsums[(size_t)s * 131072 + (size_t)bh * 2048 + q] = lsum;

  const int hi = (tid >> 5) & 1;
  _Float16* orow = pO + (size_t)s * 8388608 + ((size_t)bh * 2048 + q) * 64;
#pragma unroll
  for (int dta = 0; dta < 2; ++dta) {
#pragma unroll
    for (int blk = 0; blk < 4; ++blk) {
      h4 st;
#pragma unroll
      for (int e = 0; e < 4; ++e) {
        const float v = (dta == 0) ? acc0[blk * 4 + e] : acc1[blk * 4 + e];
        st[e] = (_Float16)v;
      }
      *(h4*)(orow + dta * 32 + blk * 8 + 4 * hi) = st;
    }
  }
}

// ---------------- combine partials: attno[b][q][h*64+d] = (p0+p1)/(l0+l1) ----------------
__global__ __launch_bounds__(256) void combine_k(const _Float16* __restrict__ pO,
                                                 const float* __restrict__ lsums,
                                                 _Float16* __restrict__ attno) {
  const int idx = blockIdx.x * 256 + threadIdx.x;
  const int row = idx >> 3;           // bh*2048 + q, in [0, 131072)
  const int dpart = (idx & 7) * 8;
  const int bh = row >> 11, q = row & 2047;
  const float inv = 1.0f / (lsums[row] + lsums[131072 + row]);
  const h8 a = *(const h8*)(pO + (size_t)row * 64 + dpart);
  const h8 b = *(const h8*)(pO + 8388608 + (size_t)row * 64 + dpart);
  h8 o;
#pragma unroll
  for (int e = 0; e < 8; ++e) o[e] = (_Float16)(((float)a[e] + (float)b[e]) * inv);
  const int bb = bh >> 5, h = bh & 31;
  *(h8*)(attno + ((size_t)bb * 2048 + q) * 2048 + h * 64 + dpart) = o;
}

extern "C" void kernel_launch(void* const* d_in, const int* in_sizes, int n_in,
                              void* d_out, int out_size, void* d_ws, size_t ws_size,
                              hipStream_t stream) {
  const float* x = (const float*)d_in[0];
  const float* wqkv = (const float*)d_in[1];
  const float* wout = (const float*)d_in[2];
  const float* freqs = (const float*)d_in[3];
  char* ws = (char*)d_ws;
  _Float16* xb    = (_Float16*)ws;                          // [0,16M)  gemm1 A input
  _Float16* pO    = xb;                                     // [0,32M)  attn partials (x/wqkvT dead)
  _Float16* wqkvT = (_Float16*)(ws + (size_t)(16 << 20));   // [16,40M) gemm1 B input
  float*    lsums = (float*)(ws + (size_t)(32 << 20));      // [32,33M) partial lsums (wqkvT dead)
  _Float16* woutT = (_Float16*)(ws + (size_t)(40 << 20));   // [40,48M)
  _Float16* qn    = (_Float16*)(ws + (size_t)(48 << 20));   // [48,64M) q-frags; attno after attn
  _Float16* attno = qn;                                     //          (q dead after attn)
  _Float16* kn    = (_Float16*)(ws + (size_t)(64 << 20));   // [64,80M) k-frags
  _Float16* vT    = (_Float16*)(ws + (size_t)(80 << 20));   // [80,96M) v-frags
  float* out = (float*)d_out;

  convk<<<8192, 256, 0, stream>>>(x, xb, 2 * 2048 * 2048);
  transconv_k<<<(6144 / 64) * (2048 / 64), 256, 0, stream>>>(wqkv, wqkvT, 2048, 6144);
  transconv_k<<<(2048 / 64) * (2048 / 64), 256, 0, stream>>>(wout, woutT, 2048, 2048);
  gemm_k<1><<<48 * 32, 256, 0, stream>>>(xb, wqkvT, 2048, 48, qn, kn, vT, freqs, nullptr);
  attn_k<<<2048, 256, 0, stream>>>(qn, kn, vT, pO, lsums);
  combine_k<<<4096, 256, 0, stream>>>(pO, lsums, attno);
  gemm_k<0><<<16 * 32, 256, 0, stream>>>(attno, woutT, 2048, 16, nullptr, nullptr, nullptr,
                                         nullptr, out);
}

// Round 5
// 323.660 us; speedup vs baseline: 2.9896x; 1.1190x over previous
//
#include <hip/hip_runtime.h>
#include <cstdint>

typedef _Float16 h4 __attribute__((ext_vector_type(4)));
typedef _Float16 h8 __attribute__((ext_vector_type(8)));
typedef float f32x4 __attribute__((ext_vector_type(4)));
typedef float f32x16 __attribute__((ext_vector_type(16)));

// ---------- async global->LDS, 16B per lane, wave-uniform LDS base ----------
__device__ __forceinline__ void g2l16(const void* g, void* l) {
  __builtin_amdgcn_global_load_lds(
      (__attribute__((address_space(1))) void*)(uintptr_t)(g),
      (__attribute__((address_space(3))) void*)(l), 16, 0, 0);
}

// ---------------- fp32 -> fp16 elementwise ----------------
__global__ __launch_bounds__(256) void convk(const float* __restrict__ in,
                                             _Float16* __restrict__ out, int n) {
  int i = (blockIdx.x * 256 + threadIdx.x) * 4;
  if (i + 3 < n) {
    const float4 v = *(const float4*)(in + i);
    h4 o;
    o[0] = (_Float16)v.x; o[1] = (_Float16)v.y; o[2] = (_Float16)v.z; o[3] = (_Float16)v.w;
    *(h4*)(out + i) = o;
  }
}

// ---------------- fp32 [R][C] -> fp16 [C][R] transpose-convert ----------------
__global__ __launch_bounds__(256) void transconv_k(const float* __restrict__ in,
                                                   _Float16* __restrict__ out,
                                                   int R, int C) {
  __shared__ float tile[64][65];
  const int tC = C >> 6;
  const int bc = blockIdx.x % tC, br = blockIdx.x / tC;
  const int r0 = br << 6, c0 = bc << 6;
  const int t = threadIdx.x;
  const int lr = t >> 4, lc = (t & 15) << 2;
#pragma unroll
  for (int p = 0; p < 4; ++p) {
    const float4 v = *(const float4*)(in + (size_t)(r0 + p * 16 + lr) * C + c0 + lc);
    tile[p * 16 + lr][lc + 0] = v.x;
    tile[p * 16 + lr][lc + 1] = v.y;
    tile[p * 16 + lr][lc + 2] = v.z;
    tile[p * 16 + lr][lc + 3] = v.w;
  }
  __syncthreads();
#pragma unroll
  for (int p = 0; p < 4; ++p) {
    const int oc = p * 16 + lr;  // out-row = in-col
    h4 v;
#pragma unroll
    for (int e = 0; e < 4; ++e) v[e] = (_Float16)tile[lc + e][oc];
    *(h4*)(out + (size_t)(c0 + oc) * R + r0 + lc) = v;
  }
}

// ---------------- GEMM: C[M][N] = A[M][K] * BT[N][K]^T  (fp16 in, fp32 acc) ----------------
// 2-phase double-buffered K-loop (T3-minimum): one barrier per K-step; STAGE(kt+1)
// issued AFTER the barrier so the global->LDS DMA overlaps the ds_read+MFMA of tile kt.
// The NEXT iteration's __syncthreads (vmcnt(0)+lgkmcnt(0) drain) publishes buf^1.
// Safety: writes to buf^1 during iter kt are disjoint from reads of buf (kt); the
// barrier orders all waves' reads of buf^1 (iter kt-1) before any wave's STAGE into it.
// LDS fragment map k(g,j)=8g+j for BOTH operands: one aligned ds_read_b128/fragment.
// MODE 0: plain fp32 store to fo (N = NTILES*128)
// MODE 1: QKV epilogue: l2norm + rope; q/k/v written in attn FRAGMENT ORDER:
//   [bh][blk32][frag:4][lane:64][8 fp16]  (256KB per bh per tensor)
template <int MODE>
__global__ __launch_bounds__(256) void gemm_k(
    const _Float16* __restrict__ A, const _Float16* __restrict__ BT,
    const int K, const int NTILES,
    _Float16* __restrict__ outq, _Float16* __restrict__ outk,
    _Float16* __restrict__ outv, const float* __restrict__ freqs,
    float* __restrict__ fo) {
  __shared__ __align__(16) _Float16 As[2 * 128 * 32];
  __shared__ __align__(16) _Float16 Bs[2 * 128 * 32];
  const int tid = threadIdx.x;
  // XCD-chunked + 4mb x 4bt grouped ordering: group working set ~4MB fits one XCD L2.
  // Requires gridDim.x % 8 == 0, NTILES % 4 == 0, (gridDim.x/8) / NTILES == MBC.
  const int cpx = gridDim.x >> 3;
  const int xcd = blockIdx.x & 7, idx = blockIdx.x >> 3;
  const int MBC = cpx / NTILES;  // mb rows per XCD chunk (=4 here)
  const int grp = idx >> 4, sub = idx & 15;
  const int bt = grp * 4 + (sub & 3);
  const int mb = xcd * MBC + (sub >> 2);
  const int m0 = mb * 128, n0 = bt * 128;
  const int wid = tid >> 6, lane = tid & 63;
  const int wr = wid >> 1, wc = wid & 1;
  const int g = lane >> 4, c = lane & 15;

  f32x4 acc[4][4];
#pragma unroll
  for (int i = 0; i < 4; ++i)
#pragma unroll
    for (int j = 0; j < 4; ++j)
#pragma unroll
      for (int e = 0; e < 4; ++e) acc[i][j][e] = 0.f;

  const int ldr = tid >> 2;
  const int lko = (tid & 3) * 8;
  const _Float16* ag = A + (size_t)(m0 + ldr) * K + lko;
  const _Float16* bg = BT + (size_t)(n0 + ldr) * K + lko;
  const size_t rowhop = (size_t)64 * K;
  const int wof = wid * 512;

  // prologue: stage tile 0 into buffer 0
  g2l16(ag, As + wof);
  g2l16(ag + rowhop, As + wof + 2048);
  g2l16(bg, Bs + wof);
  g2l16(bg + rowhop, Bs + wof + 2048);

  const int nk = K >> 5;
  for (int kt = 0; kt < nk; ++kt) {
    __syncthreads();  // drains vmcnt(0): STAGE(kt) complete; buf^1 reads (kt-1) done
    const int nxt = kt + 1;
    if (nxt < nk) {
      const int kof = nxt << 5;
      const int nb = (nxt & 1) * 4096;
      g2l16(ag + kof, As + nb + wof);
      g2l16(ag + rowhop + kof, As + nb + wof + 2048);
      g2l16(bg + kof, Bs + nb + wof);
      g2l16(bg + rowhop + kof, Bs + nb + wof + 2048);
    }
    const _Float16* Ab = As + (kt & 1) * 4096;
    const _Float16* Bb = Bs + (kt & 1) * 4096;
    h8 af[4], bf[4];
#pragma unroll
    for (int t = 0; t < 4; ++t) af[t] = *(const h8*)(Ab + (wr * 64 + t * 16 + c) * 32 + 8 * g);
#pragma unroll
    for (int t = 0; t < 4; ++t) bf[t] = *(const h8*)(Bb + (wc * 64 + t * 16 + c) * 32 + 8 * g);
#pragma unroll
    for (int i = 0; i < 4; ++i)
#pragma unroll
      for (int j = 0; j < 4; ++j)
        acc[i][j] = __builtin_amdgcn_mfma_f32_16x16x32_f16(af[i], bf[j], acc[i][j], 0, 0, 0);
  }

  if (MODE == 0) {
    const int Ncols = NTILES * 128;
#pragma unroll
    for (int mt = 0; mt < 4; ++mt)
#pragma unroll
      for (int i = 0; i < 4; ++i) {
        const int m = m0 + wr * 64 + mt * 16 + 4 * g + i;
        float* orow = fo + (size_t)m * Ncols + n0 + wc * 64 + c;
#pragma unroll
        for (int nt = 0; nt < 4; ++nt) orow[nt * 16] = acc[mt][nt][i];
      }
  } else {
    const int hh = ((bt & 15) << 1) | wc;  // head 0..31 within its third
    const int third = bt >> 4;             // 0=q 1=k 2=v
    if (third < 2) {
      _Float16* dst0 = (third == 0) ? outq : outk;
#pragma unroll
      for (int mt = 0; mt < 4; ++mt) {
        float ss[4];
#pragma unroll
        for (int i = 0; i < 4; ++i) {
          float s = 0.f;
#pragma unroll
          for (int nt = 0; nt < 4; ++nt) { const float v = acc[mt][nt][i]; s += v * v; }
          ss[i] = s;
        }
#pragma unroll
        for (int msk = 1; msk < 16; msk <<= 1)
#pragma unroll
          for (int i = 0; i < 4; ++i) ss[i] += __shfl_xor(ss[i], msk);
#pragma unroll
        for (int i = 0; i < 4; ++i) {
          const int m = m0 + wr * 64 + mt * 16 + 4 * g + i;
          const int b = m >> 11, pos = m & 2047;
          const float inv = 1.0f / fmaxf(sqrtf(ss[i]), 1e-12f);
          const float v0 = acc[mt][0][i] * inv, v1 = acc[mt][1][i] * inv;
          const float v2 = acc[mt][2][i] * inv, v3 = acc[mt][3][i] * inv;
          float sn, cs;
          __sincosf(freqs[pos * 32 + c], &sn, &cs);
          // fragment-order store: blk=pos>>5, frag=nt, lane=(c>>3)*32+(pos&31), elem=c&7
          _Float16* d = dst0 + ((size_t)((b << 5) | hh) * 64 + (pos >> 5)) * 2048 +
                        ((c >> 3) * 32 + (pos & 31)) * 8 + (c & 7);
          d[0]    = (_Float16)(v0 * cs - v1 * sn);
          d[512]  = (_Float16)(v1 * cs + v0 * sn);
          d[1024] = (_Float16)v2;
          d[1536] = (_Float16)v3;
        }
      }
    } else {
#pragma unroll
      for (int mt = 0; mt < 4; ++mt)
#pragma unroll
        for (int i = 0; i < 4; ++i) {
          const int m = m0 + wr * 64 + mt * 16 + 4 * g + i;
          const int b = m >> 11, pos = m & 2047;
          const int kvb = pos >> 5, sub2 = (pos >> 4) & 1, rem = pos & 15;
          const int vhi = (rem >> 2) & 1;
          const int vj = (rem & 3) + ((rem >> 3) << 2);
          const size_t hbase = ((size_t)((b << 5) | hh) * 64 + kvb) * 2048;
#pragma unroll
          for (int nt = 0; nt < 4; ++nt) {
            const int dta = nt >> 1;
            const int lfrag = vhi * 32 + (nt & 1) * 16 + c;
            outv[hbase + ((dta * 2 + sub2) * 64 + lfrag) * 8 + vj] = (_Float16)acc[mt][nt][i];
          }
        }
    }
  }
}

// ---------------- flash attention, swapped QK^T, fragment-order inputs ----------------
// 1 wave = 32 q rows of one (b,h), half the kv range. All loads: base + lane*16B
// (perfectly coalesced). Writes UNNORMALIZED partial O (fp16) + partial lsum (f32).
__global__ __launch_bounds__(256) void attn_k(const _Float16* __restrict__ qf_,
                                              const _Float16* __restrict__ kf_,
                                              const _Float16* __restrict__ vf_,
                                              _Float16* __restrict__ pO,
                                              float* __restrict__ lsums) {
  const int tid = threadIdx.x;
  const int wid = tid >> 6;
  const int lane = tid & 63;
  const int l31 = tid & 31;
  // XCD swizzle: 16 consecutive blocks (one (bh,split)) per XCD for K/V L2 residency
  const int dd = blockIdx.x;
  const int xcd = dd & 7, jb = dd >> 3;
  const int id = xcd * 16 + (jb >> 4);  // (bh,split) id in [0,128)
  const int bh = id >> 1, s = id & 1;
  const int qb = ((jb & 15) << 2) | wid;  // q-block 0..63
  const int q = qb * 32 + l31;

  const _Float16* qp = qf_ + ((size_t)bh * 64 + qb) * 2048 + lane * 8;
  h8 qfr[4];
#pragma unroll
  for (int dc = 0; dc < 4; ++dc) qfr[dc] = *(const h8*)(qp + dc * 512);

  const _Float16* kp = kf_ + ((size_t)bh * 64 + s * 32) * 2048 + lane * 8;
  const _Float16* vp = vf_ + ((size_t)bh * 64 + s * 32) * 2048 + lane * 8;

  f32x16 acc0, acc1;
#pragma unroll
  for (int e = 0; e < 16; ++e) { acc0[e] = 0.f; acc1[e] = 0.f; }
  float lsum = 0.f;
  const float C = 0.125f * 1.44269504089f;  // scale folded into exp2

  for (int it = 0; it < 32; ++it) {
    const _Float16* kb = kp + it * 2048;
    const _Float16* vb = vp + it * 2048;
    h8 kf0 = *(const h8*)(kb);
    h8 kf1 = *(const h8*)(kb + 512);
    h8 kf2 = *(const h8*)(kb + 1024);
    h8 kf3 = *(const h8*)(kb + 1536);
    h8 v00 = *(const h8*)(vb);          // dta0 sub0
    h8 v01 = *(const h8*)(vb + 512);    // dta0 sub1
    h8 v10 = *(const h8*)(vb + 1024);   // dta1 sub0
    h8 v11 = *(const h8*)(vb + 1536);   // dta1 sub1

    f32x16 S;
#pragma unroll
    for (int e = 0; e < 16; ++e) S[e] = 0.f;
    S = __builtin_amdgcn_mfma_f32_32x32x16_f16(kf0, qfr[0], S, 0, 0, 0);
    S = __builtin_amdgcn_mfma_f32_32x32x16_f16(kf1, qfr[1], S, 0, 0, 0);
    S = __builtin_amdgcn_mfma_f32_32x32x16_f16(kf2, qfr[2], S, 0, 0, 0);
    S = __builtin_amdgcn_mfma_f32_32x32x16_f16(kf3, qfr[3], S, 0, 0, 0);

    // |S|<=1 (unit q,k): exp2 safe without max-subtract
    float p[16];
#pragma unroll
    for (int e = 0; e < 16; ++e) { p[e] = exp2f(S[e] * C); lsum += p[e]; }
    h8 pb0, pb1;
#pragma unroll
    for (int e = 0; e < 8; ++e) { pb0[e] = (_Float16)p[e]; pb1[e] = (_Float16)p[e + 8]; }

    acc0 = __builtin_amdgcn_mfma_f32_32x32x16_f16(v00, pb0, acc0, 0, 0, 0);
    acc0 = __builtin_amdgcn_mfma_f32_32x32x16_f16(v01, pb1, acc0, 0, 0, 0);
    acc1 = __builtin_amdgcn_mfma_f32_32x32x16_f16(v10, pb0, acc1, 0, 0, 0);
    acc1 = __builtin_amdgcn_mfma_f32_32x32x16_f16(v11, pb1, acc1, 0, 0, 0);
  }

  lsum += __shfl_xor(lsum, 32);
  if (!(tid & 32)) lsums[(size_t)s * 131072 + (size_t)bh * 2048 + q] = lsum;

  const int hi = (tid >> 5) & 1;
  _Float16* orow = pO + (size_t)s * 8388608 + ((size_t)bh * 2048 + q) * 64;
#pragma unroll
  for (int dta = 0; dta < 2; ++dta) {
#pragma unroll
    for (int blk = 0; blk < 4; ++blk) {
      h4 st;
#pragma unroll
      for (int e = 0; e < 4; ++e) {
        const float v = (dta == 0) ? acc0[blk * 4 + e] : acc1[blk * 4 + e];
        st[e] = (_Float16)v;
      }
      *(h4*)(orow + dta * 32 + blk * 8 + 4 * hi) = st;
    }
  }
}

// ---------------- combine partials: attno[b][q][h*64+d] = (p0+p1)/(l0+l1) ----------------
__global__ __launch_bounds__(256) void combine_k(const _Float16* __restrict__ pO,
                                                 const float* __restrict__ lsums,
                                                 _Float16* __restrict__ attno) {
  const int idx = blockIdx.x * 256 + threadIdx.x;
  const int row = idx >> 3;           // bh*2048 + q, in [0, 131072)
  const int dpart = (idx & 7) * 8;
  const int bh = row >> 11, q = row & 2047;
  const float inv = 1.0f / (lsums[row] + lsums[131072 + row]);
  const h8 a = *(const h8*)(pO + (size_t)row * 64 + dpart);
  const h8 b = *(const h8*)(pO + 8388608 + (size_t)row * 64 + dpart);
  h8 o;
#pragma unroll
  for (int e = 0; e < 8; ++e) o[e] = (_Float16)(((float)a[e] + (float)b[e]) * inv);
  const int bb = bh >> 5, h = bh & 31;
  *(h8*)(attno + ((size_t)bb * 2048 + q) * 2048 + h * 64 + dpart) = o;
}

extern "C" void kernel_launch(void* const* d_in, const int* in_sizes, int n_in,
                              void* d_out, int out_size, void* d_ws, size_t ws_size,
                              hipStream_t stream) {
  const float* x = (const float*)d_in[0];
  const float* wqkv = (const float*)d_in[1];
  const float* wout = (const float*)d_in[2];
  const float* freqs = (const float*)d_in[3];
  char* ws = (char*)d_ws;
  _Float16* xb    = (_Float16*)ws;                          // [0,16M)  gemm1 A input
  _Float16* pO    = xb;                                     // [0,32M)  attn partials (x/wqkvT dead)
  _Float16* wqkvT = (_Float16*)(ws + (size_t)(16 << 20));   // [16,40M) gemm1 B input
  float*    lsums = (float*)(ws + (size_t)(32 << 20));      // [32,33M) partial lsums (wqkvT dead)
  _Float16* woutT = (_Float16*)(ws + (size_t)(40 << 20));   // [40,48M)
  _Float16* qn    = (_Float16*)(ws + (size_t)(48 << 20));   // [48,64M) q-frags; attno after attn
  _Float16* attno = qn;                                     //          (q dead after attn)
  _Float16* kn    = (_Float16*)(ws + (size_t)(64 << 20));   // [64,80M) k-frags
  _Float16* vT    = (_Float16*)(ws + (size_t)(80 << 20));   // [80,96M) v-frags
  float* out = (float*)d_out;

  convk<<<8192, 256, 0, stream>>>(x, xb, 2 * 2048 * 2048);
  transconv_k<<<(6144 / 64) * (2048 / 64), 256, 0, stream>>>(wqkv, wqkvT, 2048, 6144);
  transconv_k<<<(2048 / 64) * (2048 / 64), 256, 0, stream>>>(wout, woutT, 2048, 2048);
  gemm_k<1><<<48 * 32, 256, 0, stream>>>(xb, wqkvT, 2048, 48, qn, kn, vT, freqs, nullptr);
  attn_k<<<2048, 256, 0, stream>>>(qn, kn, vT, pO, lsums);
  combine_k<<<4096, 256, 0, stream>>>(pO, lsums, attno);
  gemm_k<0><<<16 * 32, 256, 0, stream>>>(attno, woutT, 2048, 16, nullptr, nullptr, nullptr,
                                         nullptr, out);
}

// Round 6
// 319.608 us; speedup vs baseline: 3.0275x; 1.0127x over previous
//
#include <hip/hip_runtime.h>
#include <cstdint>

typedef _Float16 h4 __attribute__((ext_vector_type(4)));
typedef _Float16 h8 __attribute__((ext_vector_type(8)));
typedef float f32x4 __attribute__((ext_vector_type(4)));
typedef float f32x16 __attribute__((ext_vector_type(16)));

// ---------- async global->LDS, 16B per lane, wave-uniform LDS base ----------
__device__ __forceinline__ void g2l16(const void* g, void* l) {
  __builtin_amdgcn_global_load_lds(
      (__attribute__((address_space(1))) void*)(uintptr_t)(g),
      (__attribute__((address_space(3))) void*)(l), 16, 0, 0);
}

// ---------------- fp32 -> fp16 elementwise ----------------
__global__ __launch_bounds__(256) void convk(const float* __restrict__ in,
                                             _Float16* __restrict__ out, int n) {
  int i = (blockIdx.x * 256 + threadIdx.x) * 4;
  if (i + 3 < n) {
    const float4 v = *(const float4*)(in + i);
    h4 o;
    o[0] = (_Float16)v.x; o[1] = (_Float16)v.y; o[2] = (_Float16)v.z; o[3] = (_Float16)v.w;
    *(h4*)(out + i) = o;
  }
}

// ---------------- fp32 [R][C] -> fp16 [C][R] transpose-convert ----------------
__global__ __launch_bounds__(256) void transconv_k(const float* __restrict__ in,
                                                   _Float16* __restrict__ out,
                                                   int R, int C) {
  __shared__ float tile[64][65];
  const int tC = C >> 6;
  const int bc = blockIdx.x % tC, br = blockIdx.x / tC;
  const int r0 = br << 6, c0 = bc << 6;
  const int t = threadIdx.x;
  const int lr = t >> 4, lc = (t & 15) << 2;
#pragma unroll
  for (int p = 0; p < 4; ++p) {
    const float4 v = *(const float4*)(in + (size_t)(r0 + p * 16 + lr) * C + c0 + lc);
    tile[p * 16 + lr][lc + 0] = v.x;
    tile[p * 16 + lr][lc + 1] = v.y;
    tile[p * 16 + lr][lc + 2] = v.z;
    tile[p * 16 + lr][lc + 3] = v.w;
  }
  __syncthreads();
#pragma unroll
  for (int p = 0; p < 4; ++p) {
    const int oc = p * 16 + lr;  // out-row = in-col
    h4 v;
#pragma unroll
    for (int e = 0; e < 4; ++e) v[e] = (_Float16)tile[lc + e][oc];
    *(h4*)(out + (size_t)(c0 + oc) * R + r0 + lc) = v;
  }
}

// ---------------- GEMM: C[M][N] = A[M][K] * BT[N][K]^T  (fp16 in, fp32 acc) ----------------
// 2-phase double-buffered K-loop: one barrier per K-step; STAGE(kt+1) issued AFTER the
// barrier so the global->LDS DMA overlaps ds_read+MFMA of tile kt.
// MODE 0: plain fp32 store to fo (N = NTILES*128)
// MODE 1: QKV epilogue: l2norm + rope; q/k/v written in attn FRAGMENT ORDER:
//   [bh][blk32][frag:4][lane:64][8 fp16]. Q additionally scaled by 0.125*log2(e)
//   (folds the attn scale + exp2 conversion; rotation is linear so it commutes).
template <int MODE>
__global__ __launch_bounds__(256) void gemm_k(
    const _Float16* __restrict__ A, const _Float16* __restrict__ BT,
    const int K, const int NTILES,
    _Float16* __restrict__ outq, _Float16* __restrict__ outk,
    _Float16* __restrict__ outv, const float* __restrict__ freqs,
    float* __restrict__ fo) {
  __shared__ __align__(16) _Float16 As[2 * 128 * 32];
  __shared__ __align__(16) _Float16 Bs[2 * 128 * 32];
  const int tid = threadIdx.x;
  // XCD-chunked + 4mb x 4bt grouped ordering: group working set ~4MB fits one XCD L2.
  const int cpx = gridDim.x >> 3;
  const int xcd = blockIdx.x & 7, idx = blockIdx.x >> 3;
  const int MBC = cpx / NTILES;
  const int grp = idx >> 4, sub = idx & 15;
  const int bt = grp * 4 + (sub & 3);
  const int mb = xcd * MBC + (sub >> 2);
  const int m0 = mb * 128, n0 = bt * 128;
  const int wid = tid >> 6, lane = tid & 63;
  const int wr = wid >> 1, wc = wid & 1;
  const int g = lane >> 4, c = lane & 15;

  f32x4 acc[4][4];
#pragma unroll
  for (int i = 0; i < 4; ++i)
#pragma unroll
    for (int j = 0; j < 4; ++j)
#pragma unroll
      for (int e = 0; e < 4; ++e) acc[i][j][e] = 0.f;

  const int ldr = tid >> 2;
  const int lko = (tid & 3) * 8;
  const _Float16* ag = A + (size_t)(m0 + ldr) * K + lko;
  const _Float16* bg = BT + (size_t)(n0 + ldr) * K + lko;
  const size_t rowhop = (size_t)64 * K;
  const int wof = wid * 512;

  // prologue: stage tile 0 into buffer 0
  g2l16(ag, As + wof);
  g2l16(ag + rowhop, As + wof + 2048);
  g2l16(bg, Bs + wof);
  g2l16(bg + rowhop, Bs + wof + 2048);

  const int nk = K >> 5;
  for (int kt = 0; kt < nk; ++kt) {
    __syncthreads();  // drains vmcnt(0): STAGE(kt) complete; buf^1 reads (kt-1) done
    const int nxt = kt + 1;
    if (nxt < nk) {
      const int kof = nxt << 5;
      const int nb = (nxt & 1) * 4096;
      g2l16(ag + kof, As + nb + wof);
      g2l16(ag + rowhop + kof, As + nb + wof + 2048);
      g2l16(bg + kof, Bs + nb + wof);
      g2l16(bg + rowhop + kof, Bs + nb + wof + 2048);
    }
    const _Float16* Ab = As + (kt & 1) * 4096;
    const _Float16* Bb = Bs + (kt & 1) * 4096;
    h8 af[4], bf[4];
#pragma unroll
    for (int t = 0; t < 4; ++t) af[t] = *(const h8*)(Ab + (wr * 64 + t * 16 + c) * 32 + 8 * g);
#pragma unroll
    for (int t = 0; t < 4; ++t) bf[t] = *(const h8*)(Bb + (wc * 64 + t * 16 + c) * 32 + 8 * g);
#pragma unroll
    for (int i = 0; i < 4; ++i)
#pragma unroll
      for (int j = 0; j < 4; ++j)
        acc[i][j] = __builtin_amdgcn_mfma_f32_16x16x32_f16(af[i], bf[j], acc[i][j], 0, 0, 0);
  }

  if (MODE == 0) {
    const int Ncols = NTILES * 128;
#pragma unroll
    for (int mt = 0; mt < 4; ++mt)
#pragma unroll
      for (int i = 0; i < 4; ++i) {
        const int m = m0 + wr * 64 + mt * 16 + 4 * g + i;
        float* orow = fo + (size_t)m * Ncols + n0 + wc * 64 + c;
#pragma unroll
        for (int nt = 0; nt < 4; ++nt) orow[nt * 16] = acc[mt][nt][i];
      }
  } else {
    const int hh = ((bt & 15) << 1) | wc;  // head 0..31 within its third
    const int third = bt >> 4;             // 0=q 1=k 2=v
    if (third < 2) {
      _Float16* dst0 = (third == 0) ? outq : outk;
#pragma unroll
      for (int mt = 0; mt < 4; ++mt) {
        float ss[4];
#pragma unroll
        for (int i = 0; i < 4; ++i) {
          float s = 0.f;
#pragma unroll
          for (int nt = 0; nt < 4; ++nt) { const float v = acc[mt][nt][i]; s += v * v; }
          ss[i] = s;
        }
#pragma unroll
        for (int msk = 1; msk < 16; msk <<= 1)
#pragma unroll
          for (int i = 0; i < 4; ++i) ss[i] += __shfl_xor(ss[i], msk);
#pragma unroll
        for (int i = 0; i < 4; ++i) {
          const int m = m0 + wr * 64 + mt * 16 + 4 * g + i;
          const int b = m >> 11, pos = m & 2047;
          float inv = 1.0f / fmaxf(sqrtf(ss[i]), 1e-12f);
          if (third == 0) inv *= 0.1803368801f;  // 0.125 * log2(e) folded into q
          const float v0 = acc[mt][0][i] * inv, v1 = acc[mt][1][i] * inv;
          const float v2 = acc[mt][2][i] * inv, v3 = acc[mt][3][i] * inv;
          float sn, cs;
          __sincosf(freqs[pos * 32 + c], &sn, &cs);
          // fragment-order store: blk=pos>>5, frag=nt, lane=(c>>3)*32+(pos&31), elem=c&7
          _Float16* d = dst0 + ((size_t)((b << 5) | hh) * 64 + (pos >> 5)) * 2048 +
                        ((c >> 3) * 32 + (pos & 31)) * 8 + (c & 7);
          d[0]    = (_Float16)(v0 * cs - v1 * sn);
          d[512]  = (_Float16)(v1 * cs + v0 * sn);
          d[1024] = (_Float16)v2;
          d[1536] = (_Float16)v3;
        }
      }
    } else {
#pragma unroll
      for (int mt = 0; mt < 4; ++mt)
#pragma unroll
        for (int i = 0; i < 4; ++i) {
          const int m = m0 + wr * 64 + mt * 16 + 4 * g + i;
          const int b = m >> 11, pos = m & 2047;
          const int kvb = pos >> 5, sub2 = (pos >> 4) & 1, rem = pos & 15;
          const int vhi = (rem >> 2) & 1;
          const int vj = (rem & 3) + ((rem >> 3) << 2);
          const size_t hbase = ((size_t)((b << 5) | hh) * 64 + kvb) * 2048;
#pragma unroll
          for (int nt = 0; nt < 4; ++nt) {
            const int dta = nt >> 1;
            const int lfrag = vhi * 32 + (nt & 1) * 16 + c;
            outv[hbase + ((dta * 2 + sub2) * 64 + lfrag) * 8 + vj] = (_Float16)acc[mt][nt][i];
          }
        }
    }
  }
}

// ---------------- flash attention, swapped QK^T, fragment-order inputs ----------------
// 1 wave = 64 q rows (2 q-blocks) of one (b,h), half the kv range: K/V L2 reads
// amortized over 2x the q rows (attn is L2-BW-bound). All loads base + lane*16B.
// Q pre-scaled by 0.125*log2e at gemm1 epilogue -> p = exp2(S) directly.
__global__ __launch_bounds__(256) void attn_k(const _Float16* __restrict__ qf_,
                                              const _Float16* __restrict__ kf_,
                                              const _Float16* __restrict__ vf_,
                                              _Float16* __restrict__ pO,
                                              float* __restrict__ lsums) {
  const int tid = threadIdx.x;
  const int wid = tid >> 6;
  const int lane = tid & 63;
  const int l31 = tid & 31;
  const int hi = (tid >> 5) & 1;
  // XCD swizzle: 8 consecutive blocks (one (bh,split)) per XCD for K/V L2 residency
  const int dd = blockIdx.x;
  const int xcd = dd & 7, jb = dd >> 3;   // jb in [0,128)
  const int id = xcd * 16 + (jb >> 3);    // (bh,split) id in [0,128)
  const int bh = id >> 1, s = id & 1;
  const int qg = jb & 7;
  const int qb0 = (qg << 3) | (wid << 1);  // even q-block 0..62
  const int q0 = qb0 * 32 + l31, q1 = q0 + 32;

  const _Float16* qp = qf_ + ((size_t)bh * 64 + qb0) * 2048 + lane * 8;
  h8 qA[4], qB[4];
#pragma unroll
  for (int dc = 0; dc < 4; ++dc) {
    qA[dc] = *(const h8*)(qp + dc * 512);
    qB[dc] = *(const h8*)(qp + 2048 + dc * 512);
  }

  const _Float16* kp = kf_ + ((size_t)bh * 64 + s * 32) * 2048 + lane * 8;
  const _Float16* vp = vf_ + ((size_t)bh * 64 + s * 32) * 2048 + lane * 8;

  f32x16 a00, a01, a10, a11;
#pragma unroll
  for (int e = 0; e < 16; ++e) { a00[e] = 0.f; a01[e] = 0.f; a10[e] = 0.f; a11[e] = 0.f; }
  float ls0 = 0.f, ls1 = 0.f;

  for (int it = 0; it < 32; ++it) {
    const _Float16* kb = kp + it * 2048;
    const _Float16* vb = vp + it * 2048;
    h8 kf0 = *(const h8*)(kb);
    h8 kf1 = *(const h8*)(kb + 512);
    h8 kf2 = *(const h8*)(kb + 1024);
    h8 kf3 = *(const h8*)(kb + 1536);
    h8 v00 = *(const h8*)(vb);          // dta0 sub0
    h8 v01 = *(const h8*)(vb + 512);    // dta0 sub1
    h8 v10 = *(const h8*)(vb + 1024);   // dta1 sub0
    h8 v11 = *(const h8*)(vb + 1536);   // dta1 sub1

    f32x16 S0, S1;
#pragma unroll
    for (int e = 0; e < 16; ++e) { S0[e] = 0.f; S1[e] = 0.f; }
    __builtin_amdgcn_s_setprio(1);
    S0 = __builtin_amdgcn_mfma_f32_32x32x16_f16(kf0, qA[0], S0, 0, 0, 0);
    S0 = __builtin_amdgcn_mfma_f32_32x32x16_f16(kf1, qA[1], S0, 0, 0, 0);
    S0 = __builtin_amdgcn_mfma_f32_32x32x16_f16(kf2, qA[2], S0, 0, 0, 0);
    S0 = __builtin_amdgcn_mfma_f32_32x32x16_f16(kf3, qA[3], S0, 0, 0, 0);
    __builtin_amdgcn_s_setprio(0);
    // p = exp2(S): scale pre-folded into q. |q.k|<=1 -> exp2 arg bounded.
    h8 pA0, pA1;
#pragma unroll
    for (int e = 0; e < 8; ++e) {
      const float pa = exp2f(S0[e]), pb = exp2f(S0[e + 8]);
      ls0 += pa + pb;
      pA0[e] = (_Float16)pa; pA1[e] = (_Float16)pb;
    }
    __builtin_amdgcn_s_setprio(1);
    S1 = __builtin_amdgcn_mfma_f32_32x32x16_f16(kf0, qB[0], S1, 0, 0, 0);
    S1 = __builtin_amdgcn_mfma_f32_32x32x16_f16(kf1, qB[1], S1, 0, 0, 0);
    S1 = __builtin_amdgcn_mfma_f32_32x32x16_f16(kf2, qB[2], S1, 0, 0, 0);
    S1 = __builtin_amdgcn_mfma_f32_32x32x16_f16(kf3, qB[3], S1, 0, 0, 0);
    __builtin_amdgcn_s_setprio(0);
    h8 pB0, pB1;
#pragma unroll
    for (int e = 0; e < 8; ++e) {
      const float pa = exp2f(S1[e]), pb = exp2f(S1[e + 8]);
      ls1 += pa + pb;
      pB0[e] = (_Float16)pa; pB1[e] = (_Float16)pb;
    }
    __builtin_amdgcn_s_setprio(1);
    a00 = __builtin_amdgcn_mfma_f32_32x32x16_f16(v00, pA0, a00, 0, 0, 0);
    a00 = __builtin_amdgcn_mfma_f32_32x32x16_f16(v01, pA1, a00, 0, 0, 0);
    a01 = __builtin_amdgcn_mfma_f32_32x32x16_f16(v10, pA0, a01, 0, 0, 0);
    a01 = __builtin_amdgcn_mfma_f32_32x32x16_f16(v11, pA1, a01, 0, 0, 0);
    a10 = __builtin_amdgcn_mfma_f32_32x32x16_f16(v00, pB0, a10, 0, 0, 0);
    a10 = __builtin_amdgcn_mfma_f32_32x32x16_f16(v01, pB1, a10, 0, 0, 0);
    a11 = __builtin_amdgcn_mfma_f32_32x32x16_f16(v10, pB0, a11, 0, 0, 0);
    a11 = __builtin_amdgcn_mfma_f32_32x32x16_f16(v11, pB1, a11, 0, 0, 0);
    __builtin_amdgcn_s_setprio(0);
  }

  ls0 += __shfl_xor(ls0, 32);
  ls1 += __shfl_xor(ls1, 32);
  if (!hi) {
    lsums[(size_t)s * 131072 + (size_t)bh * 2048 + q0] = ls0;
    lsums[(size_t)s * 131072 + (size_t)bh * 2048 + q1] = ls1;
  }

  _Float16* orow0 = pO + (size_t)s * 8388608 + ((size_t)bh * 2048 + q0) * 64;
  _Float16* orow1 = pO + (size_t)s * 8388608 + ((size_t)bh * 2048 + q1) * 64;
#pragma unroll
  for (int dta = 0; dta < 2; ++dta) {
#pragma unroll
    for (int blk = 0; blk < 4; ++blk) {
      h4 st0, st1;
#pragma unroll
      for (int e = 0; e < 4; ++e) {
        st0[e] = (_Float16)((dta == 0) ? a00[blk * 4 + e] : a01[blk * 4 + e]);
        st1[e] = (_Float16)((dta == 0) ? a10[blk * 4 + e] : a11[blk * 4 + e]);
      }
      *(h4*)(orow0 + dta * 32 + blk * 8 + 4 * hi) = st0;
      *(h4*)(orow1 + dta * 32 + blk * 8 + 4 * hi) = st1;
    }
  }
}

// ---------------- combine partials: attno[b][q][h*64+d] = (p0+p1)/(l0+l1) ----------------
__global__ __launch_bounds__(256) void combine_k(const _Float16* __restrict__ pO,
                                                 const float* __restrict__ lsums,
                                                 _Float16* __restrict__ attno) {
  const int idx = blockIdx.x * 256 + threadIdx.x;
  const int row = idx >> 3;           // bh*2048 + q, in [0, 131072)
  const int dpart = (idx & 7) * 8;
  const int bh = row >> 11, q = row & 2047;
  const float inv = 1.0f / (lsums[row] + lsums[131072 + row]);
  const h8 a = *(const h8*)(pO + (size_t)row * 64 + dpart);
  const h8 b = *(const h8*)(pO + 8388608 + (size_t)row * 64 + dpart);
  h8 o;
#pragma unroll
  for (int e = 0; e < 8; ++e) o[e] = (_Float16)(((float)a[e] + (float)b[e]) * inv);
  const int bb = bh >> 5, h = bh & 31;
  *(h8*)(attno + ((size_t)bb * 2048 + q) * 2048 + h * 64 + dpart) = o;
}

extern "C" void kernel_launch(void* const* d_in, const int* in_sizes, int n_in,
                              void* d_out, int out_size, void* d_ws, size_t ws_size,
                              hipStream_t stream) {
  const float* x = (const float*)d_in[0];
  const float* wqkv = (const float*)d_in[1];
  const float* wout = (const float*)d_in[2];
  const float* freqs = (const float*)d_in[3];
  char* ws = (char*)d_ws;
  _Float16* xb    = (_Float16*)ws;                          // [0,16M)  gemm1 A input
  _Float16* pO    = xb;                                     // [0,32M)  attn partials (x/wqkvT dead)
  _Float16* wqkvT = (_Float16*)(ws + (size_t)(16 << 20));   // [16,40M) gemm1 B input
  float*    lsums = (float*)(ws + (size_t)(32 << 20));      // [32,33M) partial lsums (wqkvT dead)
  _Float16* woutT = (_Float16*)(ws + (size_t)(40 << 20));   // [40,48M)
  _Float16* qn    = (_Float16*)(ws + (size_t)(48 << 20));   // [48,64M) q-frags; attno after attn
  _Float16* attno = qn;                                     //          (q dead after attn)
  _Float16* kn    = (_Float16*)(ws + (size_t)(64 << 20));   // [64,80M) k-frags
  _Float16* vT    = (_Float16*)(ws + (size_t)(80 << 20));   // [80,96M) v-frags
  float* out = (float*)d_out;

  convk<<<8192, 256, 0, stream>>>(x, xb, 2 * 2048 * 2048);
  transconv_k<<<(6144 / 64) * (2048 / 64), 256, 0, stream>>>(wqkv, wqkvT, 2048, 6144);
  transconv_k<<<(2048 / 64) * (2048 / 64), 256, 0, stream>>>(wout, woutT, 2048, 2048);
  gemm_k<1><<<48 * 32, 256, 0, stream>>>(xb, wqkvT, 2048, 48, qn, kn, vT, freqs, nullptr);
  attn_k<<<1024, 256, 0, stream>>>(qn, kn, vT, pO, lsums);
  combine_k<<<4096, 256, 0, stream>>>(pO, lsums, attno);
  gemm_k<0><<<16 * 32, 256, 0, stream>>>(attno, woutT, 2048, 16, nullptr, nullptr, nullptr,
                                         nullptr, out);
}